// Round 1
// baseline (869.699 us; speedup 1.0000x reference)
//
#include <hip/hip_runtime.h>
#include <math.h>

#define N_NODES 50000
#define N_EDGES 400000
#define E_TOT   (N_EDGES + N_NODES)
#define NG      64
#define NEG_SLOPE 0.2f

// ---------------- helpers ----------------
__device__ __forceinline__ float wave_sum(float v){
#pragma unroll
  for (int off = 32; off; off >>= 1) v += __shfl_xor(v, off, 64);
  return v;
}
__device__ __forceinline__ float lrelu(float x){ return x > 0.f ? x : NEG_SLOPE * x; }

// ---------------- prep: collapse attention vectors & permute W ----------------
// wa[k][c], c in [0,16): c<8 -> src head c, c>=8 -> dst head c-8
__global__ void prep_wa_kernel(const float* __restrict__ W, const float* __restrict__ asrc,
                               const float* __restrict__ adst, float* __restrict__ wa){
  int idx = blockIdx.x * blockDim.x + threadIdx.x;
  if (idx >= 64 * 16) return;
  int k = idx >> 4, c = idx & 15;
  int h = c & 7;
  const float* a = (c < 8) ? asrc : adst;
  float s = 0.f;
#pragma unroll
  for (int d = 0; d < 64; ++d) s = fmaf(W[k * 512 + h * 64 + d], a[h * 64 + d], s);
  wa[idx] = s;
}

// W'[h*64+d][j] = W[d][h*64+j] / 8   (fold head-mean)
__global__ void prep_wp_kernel(const float* __restrict__ W, float* __restrict__ wp){
  int idx = blockIdx.x * blockDim.x + threadIdx.x;
  if (idx >= 512 * 64) return;
  int i = idx >> 6, j = idx & 63;
  int h = i >> 6, d = i & 63;
  wp[idx] = W[d * 512 + h * 64 + j] * 0.125f;
}

// ---------------- CSR build (by dst), shared across both layers ----------------
__global__ void count_kernel(const int* __restrict__ ei, int* __restrict__ counts){
  int e = blockIdx.x * blockDim.x + threadIdx.x;
  if (e >= E_TOT) return;
  int dst = (e < N_EDGES) ? ei[N_EDGES + e] : (e - N_EDGES);
  atomicAdd(&counts[dst], 1);
}

__global__ void count_batch_kernel(const int* __restrict__ batch, int* __restrict__ gcnt){
  int n = blockIdx.x * blockDim.x + threadIdx.x;
  if (n >= N_NODES) return;
  atomicAdd(&gcnt[batch[n]], 1);
}

__global__ __launch_bounds__(1024) void scan_kernel(const int* __restrict__ counts,
                                                    int* __restrict__ row_off){
  __shared__ int sh[1024];
  __shared__ int carry_s;
  if (threadIdx.x == 0) carry_s = 0;
  __syncthreads();
  for (int base = 0; base < N_NODES; base += 1024){
    int i = base + (int)threadIdx.x;
    int v = (i < N_NODES) ? counts[i] : 0;
    sh[threadIdx.x] = v;
    __syncthreads();
#pragma unroll
    for (int off = 1; off < 1024; off <<= 1){
      int add = (threadIdx.x >= (unsigned)off) ? sh[threadIdx.x - off] : 0;
      __syncthreads();
      sh[threadIdx.x] += add;
      __syncthreads();
    }
    if (i < N_NODES) row_off[i] = carry_s + sh[threadIdx.x] - v;  // exclusive
    __syncthreads();
    if (threadIdx.x == 0) carry_s += sh[1023];
    __syncthreads();
  }
  if (threadIdx.x == 0) row_off[N_NODES] = carry_s;  // == E_TOT
}

__global__ void scatter_kernel(const int* __restrict__ ei, const int* __restrict__ row_off,
                               int* __restrict__ cursor, int* __restrict__ csr_src){
  int e = blockIdx.x * blockDim.x + threadIdx.x;
  if (e >= E_TOT) return;
  int src, dst;
  if (e < N_EDGES){ src = ei[e]; dst = ei[N_EDGES + e]; }
  else            { src = dst = e - N_EDGES; }
  int pos = row_off[dst] + atomicAdd(&cursor[dst], 1);
  csr_src[pos] = src;
}

// ---------------- al = xin @ Wa  ([N,64] @ [64,16]) ----------------
__global__ void al_kernel(const float* __restrict__ xin, const float* __restrict__ wa,
                          float* __restrict__ al){
  __shared__ float w[64 * 16];
  for (int i = threadIdx.x; i < 1024; i += blockDim.x) w[i] = wa[i];
  __syncthreads();
  int idx = blockIdx.x * blockDim.x + threadIdx.x;
  if (idx >= N_NODES * 16) return;
  int n = idx >> 4, c = idx & 15;
  const float* xr = xin + n * 64;
  float s = 0.f;
#pragma unroll
  for (int k = 0; k < 64; ++k) s = fmaf(xr[k], w[k * 16 + c], s);
  al[idx] = s;
}

// ---------------- per-dst softmax + x aggregation (one wave per node) ----------------
__global__ void agg_kernel(const float* __restrict__ xin, const float* __restrict__ al,
                           const int* __restrict__ row_off, const int* __restrict__ csr_src,
                           float* __restrict__ aggx){
  int wid = (int)((blockIdx.x * blockDim.x + threadIdx.x) >> 6);
  int lane = threadIdx.x & 63;
  if (wid >= N_NODES) return;
  const int n = wid;
  const int s0 = row_off[n], s1 = row_off[n + 1];
  float ald[8];
#pragma unroll
  for (int h = 0; h < 8; ++h) ald[h] = al[n * 16 + 8 + h];

  float m[8];
#pragma unroll
  for (int h = 0; h < 8; ++h) m[h] = -1e30f;
  for (int e = s0; e < s1; ++e){
    int s = csr_src[e];
    const float* a = al + s * 16;
#pragma unroll
    for (int h = 0; h < 8; ++h){
      float l = lrelu(a[h] + ald[h]);
      m[h] = fmaxf(m[h], l);
    }
  }
  float sum[8], acc[8];
#pragma unroll
  for (int h = 0; h < 8; ++h){ sum[h] = 0.f; acc[h] = 0.f; }
  for (int e = s0; e < s1; ++e){
    int s = csr_src[e];
    const float* a = al + s * 16;
    float xv = xin[s * 64 + lane];
#pragma unroll
    for (int h = 0; h < 8; ++h){
      float l = lrelu(a[h] + ald[h]);
      float w = __expf(l - m[h]);
      sum[h] += w;
      acc[h] = fmaf(w, xv, acc[h]);
    }
  }
#pragma unroll
  for (int h = 0; h < 8; ++h)
    aggx[n * 512 + h * 64 + lane] = acc[h] / (sum[h] + 1e-16f);
}

// ---------------- Y = aggx @ W' + bias + residual  ([N,512]@[512,64]) ----------------
#define GR 128
__global__ __launch_bounds__(256) void outgemm_kernel(const float* __restrict__ A,
                                                      const float* __restrict__ B,
                                                      const float* __restrict__ bias,
                                                      const float* __restrict__ res,
                                                      float* __restrict__ Y){
  __shared__ float At[64][GR + 4];  // K-major A tile
  __shared__ float Bs[64][64];
  const int t = threadIdx.x;
  const int rowbase = blockIdx.x * GR;
  const int tr = t >> 4, tc = t & 15;
  const int r0 = tr * 8, c0 = tc * 4;
  float acc[8][4];
#pragma unroll
  for (int i = 0; i < 8; ++i)
#pragma unroll
    for (int j = 0; j < 4; ++j) acc[i][j] = 0.f;

  for (int k0 = 0; k0 < 512; k0 += 64){
#pragma unroll
    for (int ch = 0; ch < 8; ++ch){
      int flat = ch * 1024 + t * 4;
      int r = flat >> 6, kk = flat & 63;
      int grow = rowbase + r;
      float4 v = make_float4(0.f, 0.f, 0.f, 0.f);
      if (grow < N_NODES) v = *(const float4*)(A + (size_t)grow * 512 + k0 + kk);
      At[kk + 0][r] = v.x; At[kk + 1][r] = v.y; At[kk + 2][r] = v.z; At[kk + 3][r] = v.w;
    }
#pragma unroll
    for (int ch = 0; ch < 4; ++ch){
      int flat = ch * 1024 + t * 4;
      int kk = flat >> 6, cc = flat & 63;
      *(float4*)&Bs[kk][cc] = *(const float4*)(B + (k0 + kk) * 64 + cc);
    }
    __syncthreads();
#pragma unroll
    for (int k = 0; k < 64; ++k){
      float4 a0 = *(const float4*)&At[k][r0];
      float4 a1 = *(const float4*)&At[k][r0 + 4];
      float4 b  = *(const float4*)&Bs[k][c0];
      float av[8] = {a0.x, a0.y, a0.z, a0.w, a1.x, a1.y, a1.z, a1.w};
      float bv[4] = {b.x, b.y, b.z, b.w};
#pragma unroll
      for (int i = 0; i < 8; ++i)
#pragma unroll
        for (int j = 0; j < 4; ++j) acc[i][j] = fmaf(av[i], bv[j], acc[i][j]);
    }
    __syncthreads();
  }
#pragma unroll
  for (int i = 0; i < 8; ++i){
    int grow = rowbase + r0 + i;
    if (grow < N_NODES){
      float4 rv = *(const float4*)(res + (size_t)grow * 64 + c0);
      float4 o;
      o.x = acc[i][0] + bias[c0 + 0] + rv.x;
      o.y = acc[i][1] + bias[c0 + 1] + rv.y;
      o.z = acc[i][2] + bias[c0 + 2] + rv.z;
      o.w = acc[i][3] + bias[c0 + 3] + rv.w;
      *(float4*)(Y + (size_t)grow * 64 + c0) = o;
    }
  }
}

// ---------------- graph-LN stats (sum / sumsq per graph), wave per 16 nodes ----------------
__global__ void stats_kernel(const float* __restrict__ Y, const int* __restrict__ batch,
                             float* __restrict__ gs, float* __restrict__ gss){
  int w = (int)((blockIdx.x * blockDim.x + threadIdx.x) >> 6);
  int lane = threadIdx.x & 63;
  int nbase = w * 16;
  if (nbase >= N_NODES) return;
  int nend = min(nbase + 16, N_NODES);
  float s = 0.f, ss = 0.f;
  int g = batch[nbase];
  for (int n = nbase; n < nend; ++n){
    int gn = batch[n];
    if (gn != g){
      float rs = wave_sum(s), rss = wave_sum(ss);
      if (lane == 0){ atomicAdd(&gs[g], rs); atomicAdd(&gss[g], rss); }
      s = 0.f; ss = 0.f; g = gn;
    }
    float v = Y[(size_t)n * 64 + lane];
    s += v; ss = fmaf(v, v, ss);
  }
  float rs = wave_sum(s), rss = wave_sum(ss);
  if (lane == 0){ atomicAdd(&gs[g], rs); atomicAdd(&gss[g], rss); }
}

__global__ void finalize_kernel(const int* __restrict__ gcnt, const float* __restrict__ gs,
                                const float* __restrict__ gss, float* __restrict__ mean,
                                float* __restrict__ rstd){
  int g = threadIdx.x;
  if (g >= NG) return;
  float norm = fmaxf((float)gcnt[g], 1.f) * 64.f;
  float m = gs[g] / norm;
  float var = fmaxf(gss[g] / norm - m * m, 0.f);
  mean[g] = m;
  rstd[g] = rsqrtf(var + 1e-5f);
}

// ---------------- normalize + relu (layer 1) ----------------
__global__ void norm_relu_kernel(const float* __restrict__ Y, const int* __restrict__ batch,
                                 const float* __restrict__ mean, const float* __restrict__ rstd,
                                 const float* __restrict__ lw, const float* __restrict__ lb,
                                 float* __restrict__ out){
  int idx = blockIdx.x * blockDim.x + threadIdx.x;
  if (idx >= N_NODES * 64) return;
  int n = idx >> 6, c = idx & 63;
  int g = batch[n];
  float v = (Y[idx] - mean[g]) * rstd[g] * lw[c] + lb[c];
  out[idx] = fmaxf(v, 0.f);
}

// ---------------- normalize + relu + pooled accumulation (layer 2) ----------------
__global__ void norm_relu_pool_kernel(const float* __restrict__ Y, const int* __restrict__ batch,
                                      const float* __restrict__ mean, const float* __restrict__ rstd,
                                      const float* __restrict__ lw, const float* __restrict__ lb,
                                      float* __restrict__ pooled){
  int w = (int)((blockIdx.x * blockDim.x + threadIdx.x) >> 6);
  int lane = threadIdx.x & 63;
  int nbase = w * 16;
  if (nbase >= N_NODES) return;
  int nend = min(nbase + 16, N_NODES);
  float accv = 0.f;
  int g = batch[nbase];
  for (int n = nbase; n < nend; ++n){
    int gn = batch[n];
    if (gn != g){
      atomicAdd(&pooled[g * 64 + lane], accv);
      accv = 0.f; g = gn;
    }
    float v = (Y[(size_t)n * 64 + lane] - mean[g]) * rstd[g] * lw[lane] + lb[lane];
    accv += fmaxf(v, 0.f);
  }
  atomicAdd(&pooled[g * 64 + lane], accv);
}

// ---------------- head: relu(pooled/cnt @ Wh + bh) ----------------
__global__ void head_kernel(const float* __restrict__ pooled, const int* __restrict__ gcnt,
                            const float* __restrict__ Wh, const float* __restrict__ bh,
                            float* __restrict__ out){
  int idx = blockIdx.x * blockDim.x + threadIdx.x;
  if (idx >= NG * 32) return;
  int g = idx >> 5, o = idx & 31;
  float inv = 1.f / fmaxf((float)gcnt[g], 1.f);
  float s = 0.f;
#pragma unroll
  for (int d = 0; d < 64; ++d) s = fmaf(pooled[g * 64 + d] * inv, Wh[d * 32 + o], s);
  out[idx] = fmaxf(s + bh[o], 0.f);
}

// ---------------- launch ----------------
extern "C" void kernel_launch(void* const* d_in, const int* in_sizes, int n_in,
                              void* d_out, int out_size, void* d_ws, size_t ws_size,
                              hipStream_t stream){
  const float* x     = (const float*)d_in[0];
  const int*   ei    = (const int*)d_in[1];
  const int*   batch = (const int*)d_in[2];
  const float* W1    = (const float*)d_in[3];
  const float* as1   = (const float*)d_in[4];
  const float* ad1   = (const float*)d_in[5];
  const float* b1    = (const float*)d_in[6];
  const float* l1w   = (const float*)d_in[7];
  const float* l1b   = (const float*)d_in[8];
  const float* W2    = (const float*)d_in[9];
  const float* as2   = (const float*)d_in[10];
  const float* ad2   = (const float*)d_in[11];
  const float* b2    = (const float*)d_in[12];
  const float* l2w   = (const float*)d_in[13];
  const float* l2b   = (const float*)d_in[14];
  const float* Wh    = (const float*)d_in[15];
  const float* bh    = (const float*)d_in[16];
  float* out = (float*)d_out;

  char* p = (char*)d_ws;
  auto alloc = [&](size_t bytes) -> void* {
    void* r = (void*)p;
    p += (bytes + 255) & ~(size_t)255;
    return r;
  };
  int*   counts  = (int*)alloc(N_NODES * 4);
  int*   row_off = (int*)alloc((N_NODES + 1) * 4);
  int*   cursor  = (int*)alloc(N_NODES * 4);
  int*   csr_src = (int*)alloc(E_TOT * 4);
  int*   gcnt    = (int*)alloc(NG * 4);
  float* wa1     = (float*)alloc(64 * 16 * 4);
  float* wa2     = (float*)alloc(64 * 16 * 4);
  float* w1p     = (float*)alloc(512 * 64 * 4);
  float* w2p     = (float*)alloc(512 * 64 * 4);
  float* al      = (float*)alloc((size_t)N_NODES * 16 * 4);
  float* aggx    = (float*)alloc((size_t)N_NODES * 512 * 4);
  float* y1p     = (float*)alloc((size_t)N_NODES * 64 * 4);
  float* y1      = (float*)alloc((size_t)N_NODES * 64 * 4);
  float* y2p     = (float*)alloc((size_t)N_NODES * 64 * 4);
  float* gstats  = (float*)alloc(8 * NG * 4);  // gs1,gss1,gs2,gss2,mean1,rstd1,mean2,rstd2
  float* pooled  = (float*)alloc(NG * 64 * 4);
  float* gs1 = gstats, *gss1 = gstats + NG, *gs2 = gstats + 2*NG, *gss2 = gstats + 3*NG;
  float* mean1 = gstats + 4*NG, *rstd1 = gstats + 5*NG, *mean2 = gstats + 6*NG, *rstd2 = gstats + 7*NG;

  hipMemsetAsync(counts, 0, N_NODES * 4, stream);
  hipMemsetAsync(cursor, 0, N_NODES * 4, stream);
  hipMemsetAsync(gcnt, 0, NG * 4, stream);
  hipMemsetAsync(gstats, 0, 8 * NG * 4, stream);
  hipMemsetAsync(pooled, 0, NG * 64 * 4, stream);

  // prep
  prep_wa_kernel<<<4, 256, 0, stream>>>(W1, as1, ad1, wa1);
  prep_wa_kernel<<<4, 256, 0, stream>>>(W2, as2, ad2, wa2);
  prep_wp_kernel<<<128, 256, 0, stream>>>(W1, w1p);
  prep_wp_kernel<<<128, 256, 0, stream>>>(W2, w2p);

  // CSR
  count_kernel<<<(E_TOT + 255) / 256, 256, 0, stream>>>(ei, counts);
  count_batch_kernel<<<(N_NODES + 255) / 256, 256, 0, stream>>>(batch, gcnt);
  scan_kernel<<<1, 1024, 0, stream>>>(counts, row_off);
  scatter_kernel<<<(E_TOT + 255) / 256, 256, 0, stream>>>(ei, row_off, cursor, csr_src);

  const int aggBlocks  = (N_NODES + 3) / 4;          // wave per node, 4 waves/block
  const int waveBlocks = ((N_NODES + 15) / 16 * 64 + 255) / 256;

  // ---- layer 1 ----
  al_kernel<<<(N_NODES * 16 + 255) / 256, 256, 0, stream>>>(x, wa1, al);
  agg_kernel<<<aggBlocks, 256, 0, stream>>>(x, al, row_off, csr_src, aggx);
  outgemm_kernel<<<(N_NODES + GR - 1) / GR, 256, 0, stream>>>(aggx, w1p, b1, x, y1p);
  stats_kernel<<<waveBlocks, 256, 0, stream>>>(y1p, batch, gs1, gss1);
  finalize_kernel<<<1, 64, 0, stream>>>(gcnt, gs1, gss1, mean1, rstd1);
  norm_relu_kernel<<<(N_NODES * 64 + 255) / 256, 256, 0, stream>>>(y1p, batch, mean1, rstd1, l1w, l1b, y1);

  // ---- layer 2 ----
  al_kernel<<<(N_NODES * 16 + 255) / 256, 256, 0, stream>>>(y1, wa2, al);
  agg_kernel<<<aggBlocks, 256, 0, stream>>>(y1, al, row_off, csr_src, aggx);
  outgemm_kernel<<<(N_NODES + GR - 1) / GR, 256, 0, stream>>>(aggx, w2p, b2, y1, y2p);
  stats_kernel<<<waveBlocks, 256, 0, stream>>>(y2p, batch, gs2, gss2);
  finalize_kernel<<<1, 64, 0, stream>>>(gcnt, gs2, gss2, mean2, rstd2);
  norm_relu_pool_kernel<<<waveBlocks, 256, 0, stream>>>(y2p, batch, mean2, rstd2, l2w, l2b, pooled);

  // ---- head ----
  head_kernel<<<(NG * 32 + 255) / 256, 256, 0, stream>>>(pooled, gcnt, Wh, bh, out);
}

// Round 2
// 551.547 us; speedup vs baseline: 1.5768x; 1.5768x over previous
//
#include <hip/hip_runtime.h>
#include <math.h>

#define N_NODES 50000
#define N_EDGES 400000
#define E_TOT   (N_EDGES + N_NODES)
#define NG      64
#define NEG_SLOPE 0.2f

// ---------------- helpers ----------------
__device__ __forceinline__ float wave_sum(float v){
#pragma unroll
  for (int off = 32; off; off >>= 1) v += __shfl_xor(v, off, 64);
  return v;
}
__device__ __forceinline__ float lrelu(float x){ return x > 0.f ? x : NEG_SLOPE * x; }

// ---------------- prep: collapse attention vectors & permute W ----------------
// wa[k][c], c in [0,16): c<8 -> src head c, c>=8 -> dst head c-8
__global__ void prep_wa_kernel(const float* __restrict__ W, const float* __restrict__ asrc,
                               const float* __restrict__ adst, float* __restrict__ wa){
  int idx = blockIdx.x * blockDim.x + threadIdx.x;
  if (idx >= 64 * 16) return;
  int k = idx >> 4, c = idx & 15;
  int h = c & 7;
  const float* a = (c < 8) ? asrc : adst;
  float s = 0.f;
#pragma unroll
  for (int d = 0; d < 64; ++d) s = fmaf(W[k * 512 + h * 64 + d], a[h * 64 + d], s);
  wa[idx] = s;
}

// W'[h*64+d][j] = W[d][h*64+j] / 8   (fold head-mean)
__global__ void prep_wp_kernel(const float* __restrict__ W, float* __restrict__ wp){
  int idx = blockIdx.x * blockDim.x + threadIdx.x;
  if (idx >= 512 * 64) return;
  int i = idx >> 6, j = idx & 63;
  int h = i >> 6, d = i & 63;
  wp[idx] = W[d * 512 + h * 64 + j] * 0.125f;
}

// ---------------- graph boundaries from sorted batch (NO atomics) ----------------
// gstart[g] = first node index with batch >= g; gstart[NG] = N_NODES
__global__ void graph_bounds_kernel(const int* __restrict__ batch, int* __restrict__ gstart){
  int n = blockIdx.x * blockDim.x + threadIdx.x;
  if (n > N_NODES) return;
  int g = (n < N_NODES) ? batch[n] : NG;
  if (n == 0){
    for (int gg = 0; gg <= g; ++gg) gstart[gg] = 0;
  } else {
    int gp = batch[n - 1];
    for (int gg = gp + 1; gg <= g; ++gg) gstart[gg] = n;
  }
}

// ---------------- CSR build (by dst), shared across both layers ----------------
__global__ void count_kernel(const int* __restrict__ ei, int* __restrict__ counts){
  int e = blockIdx.x * blockDim.x + threadIdx.x;
  if (e >= E_TOT) return;
  int dst = (e < N_EDGES) ? ei[N_EDGES + e] : (e - N_EDGES);
  atomicAdd(&counts[dst], 1);
}

// ---------- two-level exclusive scan of counts[N_NODES] -> row_off ----------
#define SCAN_B 1024
#define SCAN_NB ((N_NODES + SCAN_B - 1) / SCAN_B)   // 49

__global__ __launch_bounds__(SCAN_B) void scan1_kernel(const int* __restrict__ counts,
                                                       int* __restrict__ row_off,
                                                       int* __restrict__ blocksum){
  __shared__ int sh[SCAN_B];
  int i = blockIdx.x * SCAN_B + threadIdx.x;
  int v = (i < N_NODES) ? counts[i] : 0;
  sh[threadIdx.x] = v;
  __syncthreads();
#pragma unroll
  for (int off = 1; off < SCAN_B; off <<= 1){
    int add = (threadIdx.x >= (unsigned)off) ? sh[threadIdx.x - off] : 0;
    __syncthreads();
    sh[threadIdx.x] += add;
    __syncthreads();
  }
  if (i < N_NODES) row_off[i] = sh[threadIdx.x] - v;  // block-local exclusive
  if (threadIdx.x == SCAN_B - 1) blocksum[blockIdx.x] = sh[SCAN_B - 1];
}

__global__ void scan2_kernel(int* __restrict__ blocksum, int* __restrict__ blockoff){
  // single wave is enough for 49 values
  __shared__ int sh[64];
  int t = threadIdx.x;
  int v = (t < SCAN_NB) ? blocksum[t] : 0;
  sh[t] = v;
  __syncthreads();
#pragma unroll
  for (int off = 1; off < 64; off <<= 1){
    int add = (t >= off) ? sh[t - off] : 0;
    __syncthreads();
    sh[t] += add;
    __syncthreads();
  }
  if (t < SCAN_NB) blockoff[t] = sh[t] - v;   // exclusive
  if (t == 63) blockoff[SCAN_NB] = sh[63];    // total == E_TOT
}

__global__ void scan3_kernel(int* __restrict__ row_off, const int* __restrict__ blockoff){
  int i = blockIdx.x * blockDim.x + threadIdx.x;
  if (i < N_NODES) row_off[i] += blockoff[i >> 10];
  if (i == 0) row_off[N_NODES] = blockoff[SCAN_NB];
}

__global__ void scatter_kernel(const int* __restrict__ ei, const int* __restrict__ row_off,
                               int* __restrict__ cursor, int* __restrict__ csr_src){
  int e = blockIdx.x * blockDim.x + threadIdx.x;
  if (e >= E_TOT) return;
  int src, dst;
  if (e < N_EDGES){ src = ei[e]; dst = ei[N_EDGES + e]; }
  else            { src = dst = e - N_EDGES; }
  int pos = row_off[dst] + atomicAdd(&cursor[dst], 1);
  csr_src[pos] = src;
}

// ---------------- al = xin @ Wa  ([N,64] @ [64,16]) ----------------
__global__ void al_kernel(const float* __restrict__ xin, const float* __restrict__ wa,
                          float* __restrict__ al){
  __shared__ float w[64 * 16];
  for (int i = threadIdx.x; i < 1024; i += blockDim.x) w[i] = wa[i];
  __syncthreads();
  int idx = blockIdx.x * blockDim.x + threadIdx.x;
  if (idx >= N_NODES * 16) return;
  int n = idx >> 4, c = idx & 15;
  const float* xr = xin + n * 64;
  float s = 0.f;
#pragma unroll
  for (int k = 0; k < 64; ++k) s = fmaf(xr[k], w[k * 16 + c], s);
  al[idx] = s;
}

// ---------------- per-dst softmax + x aggregation (one wave per node) ----------------
__global__ void agg_kernel(const float* __restrict__ xin, const float* __restrict__ al,
                           const int* __restrict__ row_off, const int* __restrict__ csr_src,
                           float* __restrict__ aggx){
  int wid = (int)((blockIdx.x * blockDim.x + threadIdx.x) >> 6);
  int lane = threadIdx.x & 63;
  if (wid >= N_NODES) return;
  const int n = wid;
  const int s0 = row_off[n], s1 = row_off[n + 1];
  float ald[8];
#pragma unroll
  for (int h = 0; h < 8; ++h) ald[h] = al[n * 16 + 8 + h];

  float m[8];
#pragma unroll
  for (int h = 0; h < 8; ++h) m[h] = -1e30f;
  for (int e = s0; e < s1; ++e){
    int s = csr_src[e];
    const float* a = al + s * 16;
#pragma unroll
    for (int h = 0; h < 8; ++h){
      float l = lrelu(a[h] + ald[h]);
      m[h] = fmaxf(m[h], l);
    }
  }
  float sum[8], acc[8];
#pragma unroll
  for (int h = 0; h < 8; ++h){ sum[h] = 0.f; acc[h] = 0.f; }
  for (int e = s0; e < s1; ++e){
    int s = csr_src[e];
    const float* a = al + s * 16;
    float xv = xin[s * 64 + lane];
#pragma unroll
    for (int h = 0; h < 8; ++h){
      float l = lrelu(a[h] + ald[h]);
      float w = __expf(l - m[h]);
      sum[h] += w;
      acc[h] = fmaf(w, xv, acc[h]);
    }
  }
#pragma unroll
  for (int h = 0; h < 8; ++h)
    aggx[n * 512 + h * 64 + lane] = acc[h] / (sum[h] + 1e-16f);
}

// ---------------- Y = aggx @ W' + bias + residual  ([N,512]@[512,64]) ----------------
#define GR 128
__global__ __launch_bounds__(256) void outgemm_kernel(const float* __restrict__ A,
                                                      const float* __restrict__ B,
                                                      const float* __restrict__ bias,
                                                      const float* __restrict__ res,
                                                      float* __restrict__ Y){
  __shared__ float At[64][GR + 4];  // K-major A tile
  __shared__ float Bs[64][64];
  const int t = threadIdx.x;
  const int rowbase = blockIdx.x * GR;
  const int tr = t >> 4, tc = t & 15;
  const int r0 = tr * 8, c0 = tc * 4;
  float acc[8][4];
#pragma unroll
  for (int i = 0; i < 8; ++i)
#pragma unroll
    for (int j = 0; j < 4; ++j) acc[i][j] = 0.f;

  for (int k0 = 0; k0 < 512; k0 += 64){
#pragma unroll
    for (int ch = 0; ch < 8; ++ch){
      int flat = ch * 1024 + t * 4;
      int r = flat >> 6, kk = flat & 63;
      int grow = rowbase + r;
      float4 v = make_float4(0.f, 0.f, 0.f, 0.f);
      if (grow < N_NODES) v = *(const float4*)(A + (size_t)grow * 512 + k0 + kk);
      At[kk + 0][r] = v.x; At[kk + 1][r] = v.y; At[kk + 2][r] = v.z; At[kk + 3][r] = v.w;
    }
#pragma unroll
    for (int ch = 0; ch < 4; ++ch){
      int flat = ch * 1024 + t * 4;
      int kk = flat >> 6, cc = flat & 63;
      *(float4*)&Bs[kk][cc] = *(const float4*)(B + (k0 + kk) * 64 + cc);
    }
    __syncthreads();
#pragma unroll
    for (int k = 0; k < 64; ++k){
      float4 a0 = *(const float4*)&At[k][r0];
      float4 a1 = *(const float4*)&At[k][r0 + 4];
      float4 b  = *(const float4*)&Bs[k][c0];
      float av[8] = {a0.x, a0.y, a0.z, a0.w, a1.x, a1.y, a1.z, a1.w};
      float bv[4] = {b.x, b.y, b.z, b.w};
#pragma unroll
      for (int i = 0; i < 8; ++i)
#pragma unroll
        for (int j = 0; j < 4; ++j) acc[i][j] = fmaf(av[i], bv[j], acc[i][j]);
    }
    __syncthreads();
  }
#pragma unroll
  for (int i = 0; i < 8; ++i){
    int grow = rowbase + r0 + i;
    if (grow < N_NODES){
      float4 rv = *(const float4*)(res + (size_t)grow * 64 + c0);
      float4 o;
      o.x = acc[i][0] + bias[c0 + 0] + rv.x;
      o.y = acc[i][1] + bias[c0 + 1] + rv.y;
      o.z = acc[i][2] + bias[c0 + 2] + rv.z;
      o.w = acc[i][3] + bias[c0 + 3] + rv.w;
      *(float4*)(Y + (size_t)grow * 64 + c0) = o;
    }
  }
}

// ---------------- graph-LN stats (sum / sumsq per graph), wave per 16 nodes ----------------
__global__ void stats_kernel(const float* __restrict__ Y, const int* __restrict__ batch,
                             float* __restrict__ gs, float* __restrict__ gss){
  int w = (int)((blockIdx.x * blockDim.x + threadIdx.x) >> 6);
  int lane = threadIdx.x & 63;
  int nbase = w * 16;
  if (nbase >= N_NODES) return;
  int nend = min(nbase + 16, N_NODES);
  float s = 0.f, ss = 0.f;
  int g = batch[nbase];
  for (int n = nbase; n < nend; ++n){
    int gn = batch[n];
    if (gn != g){
      float rs = wave_sum(s), rss = wave_sum(ss);
      if (lane == 0){ atomicAdd(&gs[g], rs); atomicAdd(&gss[g], rss); }
      s = 0.f; ss = 0.f; g = gn;
    }
    float v = Y[(size_t)n * 64 + lane];
    s += v; ss = fmaf(v, v, ss);
  }
  float rs = wave_sum(s), rss = wave_sum(ss);
  if (lane == 0){ atomicAdd(&gs[g], rs); atomicAdd(&gss[g], rss); }
}

__global__ void finalize_kernel(const int* __restrict__ gstart, const float* __restrict__ gs,
                                const float* __restrict__ gss, float* __restrict__ mean,
                                float* __restrict__ rstd){
  int g = threadIdx.x;
  if (g >= NG) return;
  float cnt = (float)(gstart[g + 1] - gstart[g]);
  float norm = fmaxf(cnt, 1.f) * 64.f;
  float m = gs[g] / norm;
  float var = fmaxf(gss[g] / norm - m * m, 0.f);
  mean[g] = m;
  rstd[g] = rsqrtf(var + 1e-5f);
}

// ---------------- normalize + relu (layer 1) ----------------
__global__ void norm_relu_kernel(const float* __restrict__ Y, const int* __restrict__ batch,
                                 const float* __restrict__ mean, const float* __restrict__ rstd,
                                 const float* __restrict__ lw, const float* __restrict__ lb,
                                 float* __restrict__ out){
  int idx = blockIdx.x * blockDim.x + threadIdx.x;
  if (idx >= N_NODES * 64) return;
  int n = idx >> 6, c = idx & 63;
  int g = batch[n];
  float v = (Y[idx] - mean[g]) * rstd[g] * lw[c] + lb[c];
  out[idx] = fmaxf(v, 0.f);
}

// ---------------- normalize + relu + pooled accumulation (layer 2) ----------------
__global__ void norm_relu_pool_kernel(const float* __restrict__ Y, const int* __restrict__ batch,
                                      const float* __restrict__ mean, const float* __restrict__ rstd,
                                      const float* __restrict__ lw, const float* __restrict__ lb,
                                      float* __restrict__ pooled){
  int w = (int)((blockIdx.x * blockDim.x + threadIdx.x) >> 6);
  int lane = threadIdx.x & 63;
  int nbase = w * 16;
  if (nbase >= N_NODES) return;
  int nend = min(nbase + 16, N_NODES);
  float accv = 0.f;
  int g = batch[nbase];
  for (int n = nbase; n < nend; ++n){
    int gn = batch[n];
    if (gn != g){
      atomicAdd(&pooled[g * 64 + lane], accv);
      accv = 0.f; g = gn;
    }
    float v = (Y[(size_t)n * 64 + lane] - mean[g]) * rstd[g] * lw[lane] + lb[lane];
    accv += fmaxf(v, 0.f);
  }
  atomicAdd(&pooled[g * 64 + lane], accv);
}

// ---------------- head: relu(pooled/cnt @ Wh + bh) ----------------
__global__ void head_kernel(const float* __restrict__ pooled, const int* __restrict__ gstart,
                            const float* __restrict__ Wh, const float* __restrict__ bh,
                            float* __restrict__ out){
  int idx = blockIdx.x * blockDim.x + threadIdx.x;
  if (idx >= NG * 32) return;
  int g = idx >> 5, o = idx & 31;
  float cnt = (float)(gstart[g + 1] - gstart[g]);
  float inv = 1.f / fmaxf(cnt, 1.f);
  float s = 0.f;
#pragma unroll
  for (int d = 0; d < 64; ++d) s = fmaf(pooled[g * 64 + d] * inv, Wh[d * 32 + o], s);
  out[idx] = fmaxf(s + bh[o], 0.f);
}

// ---------------- launch ----------------
extern "C" void kernel_launch(void* const* d_in, const int* in_sizes, int n_in,
                              void* d_out, int out_size, void* d_ws, size_t ws_size,
                              hipStream_t stream){
  const float* x     = (const float*)d_in[0];
  const int*   ei    = (const int*)d_in[1];
  const int*   batch = (const int*)d_in[2];
  const float* W1    = (const float*)d_in[3];
  const float* as1   = (const float*)d_in[4];
  const float* ad1   = (const float*)d_in[5];
  const float* b1    = (const float*)d_in[6];
  const float* l1w   = (const float*)d_in[7];
  const float* l1b   = (const float*)d_in[8];
  const float* W2    = (const float*)d_in[9];
  const float* as2   = (const float*)d_in[10];
  const float* ad2   = (const float*)d_in[11];
  const float* b2    = (const float*)d_in[12];
  const float* l2w   = (const float*)d_in[13];
  const float* l2b   = (const float*)d_in[14];
  const float* Wh    = (const float*)d_in[15];
  const float* bh    = (const float*)d_in[16];
  float* out = (float*)d_out;

  char* p = (char*)d_ws;
  auto alloc = [&](size_t bytes) -> void* {
    void* r = (void*)p;
    p += (bytes + 255) & ~(size_t)255;
    return r;
  };
  int*   counts   = (int*)alloc(N_NODES * 4);
  int*   row_off  = (int*)alloc((N_NODES + 1) * 4);
  int*   cursor   = (int*)alloc(N_NODES * 4);
  int*   csr_src  = (int*)alloc(E_TOT * 4);
  int*   gstart   = (int*)alloc((NG + 1) * 4);
  int*   blocksum = (int*)alloc((SCAN_NB + 1) * 4);
  int*   blockoff = (int*)alloc((SCAN_NB + 1) * 4);
  float* wa1      = (float*)alloc(64 * 16 * 4);
  float* wa2      = (float*)alloc(64 * 16 * 4);
  float* w1p      = (float*)alloc(512 * 64 * 4);
  float* w2p      = (float*)alloc(512 * 64 * 4);
  float* al       = (float*)alloc((size_t)N_NODES * 16 * 4);
  float* aggx     = (float*)alloc((size_t)N_NODES * 512 * 4);
  float* y1p      = (float*)alloc((size_t)N_NODES * 64 * 4);
  float* y1       = (float*)alloc((size_t)N_NODES * 64 * 4);
  float* y2p      = (float*)alloc((size_t)N_NODES * 64 * 4);
  float* gstats   = (float*)alloc(8 * NG * 4);
  float* pooled   = (float*)alloc(NG * 64 * 4);
  float* gs1 = gstats, *gss1 = gstats + NG, *gs2 = gstats + 2*NG, *gss2 = gstats + 3*NG;
  float* mean1 = gstats + 4*NG, *rstd1 = gstats + 5*NG, *mean2 = gstats + 6*NG, *rstd2 = gstats + 7*NG;

  hipMemsetAsync(counts, 0, N_NODES * 4, stream);
  hipMemsetAsync(cursor, 0, N_NODES * 4, stream);
  hipMemsetAsync(gstats, 0, 8 * NG * 4, stream);
  hipMemsetAsync(pooled, 0, NG * 64 * 4, stream);

  // prep
  prep_wa_kernel<<<4, 256, 0, stream>>>(W1, as1, ad1, wa1);
  prep_wa_kernel<<<4, 256, 0, stream>>>(W2, as2, ad2, wa2);
  prep_wp_kernel<<<128, 256, 0, stream>>>(W1, w1p);
  prep_wp_kernel<<<128, 256, 0, stream>>>(W2, w2p);

  // graph bounds (no atomics — batch is sorted)
  graph_bounds_kernel<<<(N_NODES + 256) / 256, 256, 0, stream>>>(batch, gstart);

  // CSR
  count_kernel<<<(E_TOT + 255) / 256, 256, 0, stream>>>(ei, counts);
  scan1_kernel<<<SCAN_NB, SCAN_B, 0, stream>>>(counts, row_off, blocksum);
  scan2_kernel<<<1, 64, 0, stream>>>(blocksum, blockoff);
  scan3_kernel<<<(N_NODES + 255) / 256, 256, 0, stream>>>(row_off, blockoff);
  scatter_kernel<<<(E_TOT + 255) / 256, 256, 0, stream>>>(ei, row_off, cursor, csr_src);

  const int aggBlocks  = (N_NODES + 3) / 4;          // wave per node, 4 waves/block
  const int waveBlocks = ((N_NODES + 15) / 16 * 64 + 255) / 256;

  // ---- layer 1 ----
  al_kernel<<<(N_NODES * 16 + 255) / 256, 256, 0, stream>>>(x, wa1, al);
  agg_kernel<<<aggBlocks, 256, 0, stream>>>(x, al, row_off, csr_src, aggx);
  outgemm_kernel<<<(N_NODES + GR - 1) / GR, 256, 0, stream>>>(aggx, w1p, b1, x, y1p);
  stats_kernel<<<waveBlocks, 256, 0, stream>>>(y1p, batch, gs1, gss1);
  finalize_kernel<<<1, 64, 0, stream>>>(gstart, gs1, gss1, mean1, rstd1);
  norm_relu_kernel<<<(N_NODES * 64 + 255) / 256, 256, 0, stream>>>(y1p, batch, mean1, rstd1, l1w, l1b, y1);

  // ---- layer 2 ----
  al_kernel<<<(N_NODES * 16 + 255) / 256, 256, 0, stream>>>(y1, wa2, al);
  agg_kernel<<<aggBlocks, 256, 0, stream>>>(y1, al, row_off, csr_src, aggx);
  outgemm_kernel<<<(N_NODES + GR - 1) / GR, 256, 0, stream>>>(aggx, w2p, b2, y1, y2p);
  stats_kernel<<<waveBlocks, 256, 0, stream>>>(y2p, batch, gs2, gss2);
  finalize_kernel<<<1, 64, 0, stream>>>(gstart, gs2, gss2, mean2, rstd2);
  norm_relu_pool_kernel<<<waveBlocks, 256, 0, stream>>>(y2p, batch, mean2, rstd2, l2w, l2b, pooled);

  // ---- head ----
  head_kernel<<<(NG * 32 + 255) / 256, 256, 0, stream>>>(pooled, gstart, Wh, bh, out);
}

// Round 3
// 478.058 us; speedup vs baseline: 1.8192x; 1.1537x over previous
//
#include <hip/hip_runtime.h>
#include <math.h>

#define N_NODES 50000
#define N_EDGES 400000
#define E_TOT   (N_EDGES + N_NODES)
#define NG      64
#define NEG_SLOPE 0.2f

// ---------------- helpers ----------------
__device__ __forceinline__ float wave_sum(float v){
#pragma unroll
  for (int off = 32; off; off >>= 1) v += __shfl_xor(v, off, 64);
  return v;
}
__device__ __forceinline__ float lrelu(float x){ return x > 0.f ? x : NEG_SLOPE * x; }

// ---------------- prep: collapse attention vectors & permute W ----------------
__global__ void prep_wa_kernel(const float* __restrict__ W, const float* __restrict__ asrc,
                               const float* __restrict__ adst, float* __restrict__ wa){
  int idx = blockIdx.x * blockDim.x + threadIdx.x;
  if (idx >= 64 * 16) return;
  int k = idx >> 4, c = idx & 15;
  int h = c & 7;
  const float* a = (c < 8) ? asrc : adst;
  float s = 0.f;
#pragma unroll
  for (int d = 0; d < 64; ++d) s = fmaf(W[k * 512 + h * 64 + d], a[h * 64 + d], s);
  wa[idx] = s;
}

// W'[h*64+d][j] = W[d][h*64+j] / 8   (fold head-mean)
__global__ void prep_wp_kernel(const float* __restrict__ W, float* __restrict__ wp){
  int idx = blockIdx.x * blockDim.x + threadIdx.x;
  if (idx >= 512 * 64) return;
  int i = idx >> 6, j = idx & 63;
  int h = i >> 6, d = i & 63;
  wp[idx] = W[d * 512 + h * 64 + j] * 0.125f;
}

// ---------------- graph boundaries from sorted batch (NO atomics) ----------------
__global__ void graph_bounds_kernel(const int* __restrict__ batch, int* __restrict__ gstart){
  int n = blockIdx.x * blockDim.x + threadIdx.x;
  if (n > N_NODES) return;
  int g = (n < N_NODES) ? batch[n] : NG;
  if (n == 0){
    for (int gg = 0; gg <= g; ++gg) gstart[gg] = 0;
  } else {
    int gp = batch[n - 1];
    for (int gg = gp + 1; gg <= g; ++gg) gstart[gg] = n;
  }
}

// ---------------- CSR build (by dst), shared across both layers ----------------
__global__ void count_kernel(const int* __restrict__ ei, int* __restrict__ counts){
  int e = blockIdx.x * blockDim.x + threadIdx.x;
  if (e >= E_TOT) return;
  int dst = (e < N_EDGES) ? ei[N_EDGES + e] : (e - N_EDGES);
  atomicAdd(&counts[dst], 1);
}

#define SCAN_B 1024
#define SCAN_NB ((N_NODES + SCAN_B - 1) / SCAN_B)   // 49

__global__ __launch_bounds__(SCAN_B) void scan1_kernel(const int* __restrict__ counts,
                                                       int* __restrict__ row_off,
                                                       int* __restrict__ blocksum){
  __shared__ int sh[SCAN_B];
  int i = blockIdx.x * SCAN_B + threadIdx.x;
  int v = (i < N_NODES) ? counts[i] : 0;
  sh[threadIdx.x] = v;
  __syncthreads();
#pragma unroll
  for (int off = 1; off < SCAN_B; off <<= 1){
    int add = (threadIdx.x >= (unsigned)off) ? sh[threadIdx.x - off] : 0;
    __syncthreads();
    sh[threadIdx.x] += add;
    __syncthreads();
  }
  if (i < N_NODES) row_off[i] = sh[threadIdx.x] - v;
  if (threadIdx.x == SCAN_B - 1) blocksum[blockIdx.x] = sh[SCAN_B - 1];
}

__global__ void scan2_kernel(int* __restrict__ blocksum, int* __restrict__ blockoff){
  __shared__ int sh[64];
  int t = threadIdx.x;
  int v = (t < SCAN_NB) ? blocksum[t] : 0;
  sh[t] = v;
  __syncthreads();
#pragma unroll
  for (int off = 1; off < 64; off <<= 1){
    int add = (t >= off) ? sh[t - off] : 0;
    __syncthreads();
    sh[t] += add;
    __syncthreads();
  }
  if (t < SCAN_NB) blockoff[t] = sh[t] - v;
  if (t == 63) blockoff[SCAN_NB] = sh[63];
}

__global__ void scan3_kernel(int* __restrict__ row_off, const int* __restrict__ blockoff){
  int i = blockIdx.x * blockDim.x + threadIdx.x;
  if (i < N_NODES) row_off[i] += blockoff[i >> 10];
  if (i == 0) row_off[N_NODES] = blockoff[SCAN_NB];
}

__global__ void scatter_kernel(const int* __restrict__ ei, const int* __restrict__ row_off,
                               int* __restrict__ cursor, int* __restrict__ csr_src){
  int e = blockIdx.x * blockDim.x + threadIdx.x;
  if (e >= E_TOT) return;
  int src, dst;
  if (e < N_EDGES){ src = ei[e]; dst = ei[N_EDGES + e]; }
  else            { src = dst = e - N_EDGES; }
  int pos = row_off[dst] + atomicAdd(&cursor[dst], 1);
  csr_src[pos] = src;
}

// ---------------- al = xin @ Wa  ([N,64] @ [64,16]) ----------------
__global__ void al_kernel(const float* __restrict__ xin, const float* __restrict__ wa,
                          float* __restrict__ al){
  __shared__ float w[64 * 16];
  for (int i = threadIdx.x; i < 1024; i += blockDim.x) w[i] = wa[i];
  __syncthreads();
  int idx = blockIdx.x * blockDim.x + threadIdx.x;
  if (idx >= N_NODES * 16) return;
  int n = idx >> 4, c = idx & 15;
  const float* xr = xin + n * 64;
  float s = 0.f;
#pragma unroll
  for (int k = 0; k < 64; ++k) s = fmaf(xr[k], w[k * 16 + c], s);
  al[idx] = s;
}

// ---------------- softmax weights per (edge, head): lane-parallel ----------------
// wave per node; lane = eo*8 + h (eo: edge slot 0..7, h: head)
__global__ void weights_kernel(const float* __restrict__ al, const int* __restrict__ row_off,
                               const int* __restrict__ csr_src, float* __restrict__ ew,
                               float* __restrict__ nsum){
  int wid = (int)((blockIdx.x * blockDim.x + threadIdx.x) >> 6);
  int lane = threadIdx.x & 63;
  if (wid >= N_NODES) return;
  const int n = wid;
  const int eo = lane >> 3, h = lane & 7;
  const int s0 = row_off[n], s1 = row_off[n + 1];
  const float ald = al[n * 16 + 8 + h];

  // pass 1: running max (per lane over its edge slots)
  float m = -1e30f;
  for (int e = s0 + eo; e < s1; e += 8){
    int s = csr_src[e];
    m = fmaxf(m, lrelu(al[s * 16 + h] + ald));
  }
#pragma unroll
  for (int off = 8; off < 64; off <<= 1) m = fmaxf(m, __shfl_xor(m, off, 64));

  // pass 2: exp + store + sum
  float sum = 0.f;
  for (int e = s0 + eo; e < s1; e += 8){
    int s = csr_src[e];
    float l = lrelu(al[s * 16 + h] + ald);
    float w = __expf(l - m);
    sum += w;
    ew[(size_t)e * 8 + h] = w;
  }
#pragma unroll
  for (int off = 8; off < 64; off <<= 1) sum += __shfl_xor(sum, off, 64);
  if (lane < 8) nsum[n * 8 + lane] = sum;
}

// ---------------- aggregation: wave per node, lane = dim ----------------
__global__ void agg2_kernel(const float* __restrict__ xin, const float* __restrict__ ew,
                            const float* __restrict__ nsum, const int* __restrict__ row_off,
                            const int* __restrict__ csr_src, float* __restrict__ aggx){
  int wid = (int)((blockIdx.x * blockDim.x + threadIdx.x) >> 6);
  int lane = threadIdx.x & 63;
  if (wid >= N_NODES) return;
  const int n = wid;
  const int s0 = row_off[n], s1 = row_off[n + 1];
  float acc[8];
#pragma unroll
  for (int h = 0; h < 8; ++h) acc[h] = 0.f;

  for (int e = s0; e < s1; ++e){
    int s = csr_src[e];
    float xv = xin[s * 64 + lane];
    float4 w0 = *(const float4*)(ew + (size_t)e * 8);
    float4 w1 = *(const float4*)(ew + (size_t)e * 8 + 4);
    acc[0] = fmaf(w0.x, xv, acc[0]);
    acc[1] = fmaf(w0.y, xv, acc[1]);
    acc[2] = fmaf(w0.z, xv, acc[2]);
    acc[3] = fmaf(w0.w, xv, acc[3]);
    acc[4] = fmaf(w1.x, xv, acc[4]);
    acc[5] = fmaf(w1.y, xv, acc[5]);
    acc[6] = fmaf(w1.z, xv, acc[6]);
    acc[7] = fmaf(w1.w, xv, acc[7]);
  }
#pragma unroll
  for (int h = 0; h < 8; ++h)
    aggx[n * 512 + h * 64 + lane] = acc[h] / (nsum[n * 8 + h] + 1e-16f);
}

// ---------------- Y = aggx @ W' + bias + residual  ([N,512]@[512,64]) ----------------
#define GR 128
__global__ __launch_bounds__(256) void outgemm_kernel(const float* __restrict__ A,
                                                      const float* __restrict__ B,
                                                      const float* __restrict__ bias,
                                                      const float* __restrict__ res,
                                                      float* __restrict__ Y){
  __shared__ float At[64][GR + 4];
  __shared__ float Bs[64][64];
  const int t = threadIdx.x;
  const int rowbase = blockIdx.x * GR;
  const int tr = t >> 4, tc = t & 15;
  const int r0 = tr * 8, c0 = tc * 4;
  float acc[8][4];
#pragma unroll
  for (int i = 0; i < 8; ++i)
#pragma unroll
    for (int j = 0; j < 4; ++j) acc[i][j] = 0.f;

  for (int k0 = 0; k0 < 512; k0 += 64){
#pragma unroll
    for (int ch = 0; ch < 8; ++ch){
      int flat = ch * 1024 + t * 4;
      int r = flat >> 6, kk = flat & 63;
      int grow = rowbase + r;
      float4 v = make_float4(0.f, 0.f, 0.f, 0.f);
      if (grow < N_NODES) v = *(const float4*)(A + (size_t)grow * 512 + k0 + kk);
      At[kk + 0][r] = v.x; At[kk + 1][r] = v.y; At[kk + 2][r] = v.z; At[kk + 3][r] = v.w;
    }
#pragma unroll
    for (int ch = 0; ch < 4; ++ch){
      int flat = ch * 1024 + t * 4;
      int kk = flat >> 6, cc = flat & 63;
      *(float4*)&Bs[kk][cc] = *(const float4*)(B + (k0 + kk) * 64 + cc);
    }
    __syncthreads();
#pragma unroll
    for (int k = 0; k < 64; ++k){
      float4 a0 = *(const float4*)&At[k][r0];
      float4 a1 = *(const float4*)&At[k][r0 + 4];
      float4 b  = *(const float4*)&Bs[k][c0];
      float av[8] = {a0.x, a0.y, a0.z, a0.w, a1.x, a1.y, a1.z, a1.w};
      float bv[4] = {b.x, b.y, b.z, b.w};
#pragma unroll
      for (int i = 0; i < 8; ++i)
#pragma unroll
        for (int j = 0; j < 4; ++j) acc[i][j] = fmaf(av[i], bv[j], acc[i][j]);
    }
    __syncthreads();
  }
#pragma unroll
  for (int i = 0; i < 8; ++i){
    int grow = rowbase + r0 + i;
    if (grow < N_NODES){
      float4 rv = *(const float4*)(res + (size_t)grow * 64 + c0);
      float4 o;
      o.x = acc[i][0] + bias[c0 + 0] + rv.x;
      o.y = acc[i][1] + bias[c0 + 1] + rv.y;
      o.z = acc[i][2] + bias[c0 + 2] + rv.z;
      o.w = acc[i][3] + bias[c0 + 3] + rv.w;
      *(float4*)(Y + (size_t)grow * 64 + c0) = o;
    }
  }
}

// ---------------- graph-LN stats ----------------
__global__ void stats_kernel(const float* __restrict__ Y, const int* __restrict__ batch,
                             float* __restrict__ gs, float* __restrict__ gss){
  int w = (int)((blockIdx.x * blockDim.x + threadIdx.x) >> 6);
  int lane = threadIdx.x & 63;
  int nbase = w * 16;
  if (nbase >= N_NODES) return;
  int nend = min(nbase + 16, N_NODES);
  float s = 0.f, ss = 0.f;
  int g = batch[nbase];
  for (int n = nbase; n < nend; ++n){
    int gn = batch[n];
    if (gn != g){
      float rs = wave_sum(s), rss = wave_sum(ss);
      if (lane == 0){ atomicAdd(&gs[g], rs); atomicAdd(&gss[g], rss); }
      s = 0.f; ss = 0.f; g = gn;
    }
    float v = Y[(size_t)n * 64 + lane];
    s += v; ss = fmaf(v, v, ss);
  }
  float rs = wave_sum(s), rss = wave_sum(ss);
  if (lane == 0){ atomicAdd(&gs[g], rs); atomicAdd(&gss[g], rss); }
}

__global__ void finalize_kernel(const int* __restrict__ gstart, const float* __restrict__ gs,
                                const float* __restrict__ gss, float* __restrict__ mean,
                                float* __restrict__ rstd){
  int g = threadIdx.x;
  if (g >= NG) return;
  float cnt = (float)(gstart[g + 1] - gstart[g]);
  float norm = fmaxf(cnt, 1.f) * 64.f;
  float m = gs[g] / norm;
  float var = fmaxf(gss[g] / norm - m * m, 0.f);
  mean[g] = m;
  rstd[g] = rsqrtf(var + 1e-5f);
}

// ---------------- normalize + relu (layer 1) ----------------
__global__ void norm_relu_kernel(const float* __restrict__ Y, const int* __restrict__ batch,
                                 const float* __restrict__ mean, const float* __restrict__ rstd,
                                 const float* __restrict__ lw, const float* __restrict__ lb,
                                 float* __restrict__ out){
  int idx = blockIdx.x * blockDim.x + threadIdx.x;
  if (idx >= N_NODES * 64) return;
  int n = idx >> 6, c = idx & 63;
  int g = batch[n];
  float v = (Y[idx] - mean[g]) * rstd[g] * lw[c] + lb[c];
  out[idx] = fmaxf(v, 0.f);
}

// ---------------- normalize + relu + pooled accumulation (layer 2) ----------------
__global__ void norm_relu_pool_kernel(const float* __restrict__ Y, const int* __restrict__ batch,
                                      const float* __restrict__ mean, const float* __restrict__ rstd,
                                      const float* __restrict__ lw, const float* __restrict__ lb,
                                      float* __restrict__ pooled){
  int w = (int)((blockIdx.x * blockDim.x + threadIdx.x) >> 6);
  int lane = threadIdx.x & 63;
  int nbase = w * 16;
  if (nbase >= N_NODES) return;
  int nend = min(nbase + 16, N_NODES);
  float accv = 0.f;
  int g = batch[nbase];
  for (int n = nbase; n < nend; ++n){
    int gn = batch[n];
    if (gn != g){
      atomicAdd(&pooled[g * 64 + lane], accv);
      accv = 0.f; g = gn;
    }
    float v = (Y[(size_t)n * 64 + lane] - mean[g]) * rstd[g] * lw[lane] + lb[lane];
    accv += fmaxf(v, 0.f);
  }
  atomicAdd(&pooled[g * 64 + lane], accv);
}

// ---------------- head ----------------
__global__ void head_kernel(const float* __restrict__ pooled, const int* __restrict__ gstart,
                            const float* __restrict__ Wh, const float* __restrict__ bh,
                            float* __restrict__ out){
  int idx = blockIdx.x * blockDim.x + threadIdx.x;
  if (idx >= NG * 32) return;
  int g = idx >> 5, o = idx & 31;
  float cnt = (float)(gstart[g + 1] - gstart[g]);
  float inv = 1.f / fmaxf(cnt, 1.f);
  float s = 0.f;
#pragma unroll
  for (int d = 0; d < 64; ++d) s = fmaf(pooled[g * 64 + d] * inv, Wh[d * 32 + o], s);
  out[idx] = fmaxf(s + bh[o], 0.f);
}

// ---------------- launch ----------------
extern "C" void kernel_launch(void* const* d_in, const int* in_sizes, int n_in,
                              void* d_out, int out_size, void* d_ws, size_t ws_size,
                              hipStream_t stream){
  const float* x     = (const float*)d_in[0];
  const int*   ei    = (const int*)d_in[1];
  const int*   batch = (const int*)d_in[2];
  const float* W1    = (const float*)d_in[3];
  const float* as1   = (const float*)d_in[4];
  const float* ad1   = (const float*)d_in[5];
  const float* b1    = (const float*)d_in[6];
  const float* l1w   = (const float*)d_in[7];
  const float* l1b   = (const float*)d_in[8];
  const float* W2    = (const float*)d_in[9];
  const float* as2   = (const float*)d_in[10];
  const float* ad2   = (const float*)d_in[11];
  const float* b2    = (const float*)d_in[12];
  const float* l2w   = (const float*)d_in[13];
  const float* l2b   = (const float*)d_in[14];
  const float* Wh    = (const float*)d_in[15];
  const float* bh    = (const float*)d_in[16];
  float* out = (float*)d_out;

  char* p = (char*)d_ws;
  auto alloc = [&](size_t bytes) -> void* {
    void* r = (void*)p;
    p += (bytes + 255) & ~(size_t)255;
    return r;
  };
  int*   counts   = (int*)alloc(N_NODES * 4);
  int*   row_off  = (int*)alloc((N_NODES + 1) * 4);
  int*   cursor   = (int*)alloc(N_NODES * 4);
  int*   csr_src  = (int*)alloc(E_TOT * 4);
  int*   gstart   = (int*)alloc((NG + 1) * 4);
  int*   blocksum = (int*)alloc((SCAN_NB + 1) * 4);
  int*   blockoff = (int*)alloc((SCAN_NB + 1) * 4);
  float* wa1      = (float*)alloc(64 * 16 * 4);
  float* wa2      = (float*)alloc(64 * 16 * 4);
  float* w1p      = (float*)alloc(512 * 64 * 4);
  float* w2p      = (float*)alloc(512 * 64 * 4);
  float* al       = (float*)alloc((size_t)N_NODES * 16 * 4);
  float* ew       = (float*)alloc((size_t)E_TOT * 8 * 4);
  float* nsum     = (float*)alloc((size_t)N_NODES * 8 * 4);
  float* aggx     = (float*)alloc((size_t)N_NODES * 512 * 4);
  float* y1p      = (float*)alloc((size_t)N_NODES * 64 * 4);
  float* y1       = (float*)alloc((size_t)N_NODES * 64 * 4);
  float* y2p      = y1p;  // y1p is dead after layer-1 norm_relu; reuse for layer-2 pre-LN
  float* gstats   = (float*)alloc(8 * NG * 4);
  float* pooled   = (float*)alloc(NG * 64 * 4);
  float* gs1 = gstats, *gss1 = gstats + NG, *gs2 = gstats + 2*NG, *gss2 = gstats + 3*NG;
  float* mean1 = gstats + 4*NG, *rstd1 = gstats + 5*NG, *mean2 = gstats + 6*NG, *rstd2 = gstats + 7*NG;

  hipMemsetAsync(counts, 0, N_NODES * 4, stream);
  hipMemsetAsync(cursor, 0, N_NODES * 4, stream);
  hipMemsetAsync(gstats, 0, 8 * NG * 4, stream);
  hipMemsetAsync(pooled, 0, NG * 64 * 4, stream);

  // prep
  prep_wa_kernel<<<4, 256, 0, stream>>>(W1, as1, ad1, wa1);
  prep_wa_kernel<<<4, 256, 0, stream>>>(W2, as2, ad2, wa2);
  prep_wp_kernel<<<128, 256, 0, stream>>>(W1, w1p);
  prep_wp_kernel<<<128, 256, 0, stream>>>(W2, w2p);

  // graph bounds (no atomics — batch is sorted)
  graph_bounds_kernel<<<(N_NODES + 256) / 256, 256, 0, stream>>>(batch, gstart);

  // CSR
  count_kernel<<<(E_TOT + 255) / 256, 256, 0, stream>>>(ei, counts);
  scan1_kernel<<<SCAN_NB, SCAN_B, 0, stream>>>(counts, row_off, blocksum);
  scan2_kernel<<<1, 64, 0, stream>>>(blocksum, blockoff);
  scan3_kernel<<<(N_NODES + 255) / 256, 256, 0, stream>>>(row_off, blockoff);
  scatter_kernel<<<(E_TOT + 255) / 256, 256, 0, stream>>>(ei, row_off, cursor, csr_src);

  const int aggBlocks  = (N_NODES + 3) / 4;          // wave per node, 4 waves/block
  const int waveBlocks = ((N_NODES + 15) / 16 * 64 + 255) / 256;

  // ---- layer 1 ----
  al_kernel<<<(N_NODES * 16 + 255) / 256, 256, 0, stream>>>(x, wa1, al);
  weights_kernel<<<aggBlocks, 256, 0, stream>>>(al, row_off, csr_src, ew, nsum);
  agg2_kernel<<<aggBlocks, 256, 0, stream>>>(x, ew, nsum, row_off, csr_src, aggx);
  outgemm_kernel<<<(N_NODES + GR - 1) / GR, 256, 0, stream>>>(aggx, w1p, b1, x, y1p);
  stats_kernel<<<waveBlocks, 256, 0, stream>>>(y1p, batch, gs1, gss1);
  finalize_kernel<<<1, 64, 0, stream>>>(gstart, gs1, gss1, mean1, rstd1);
  norm_relu_kernel<<<(N_NODES * 64 + 255) / 256, 256, 0, stream>>>(y1p, batch, mean1, rstd1, l1w, l1b, y1);

  // ---- layer 2 ----
  al_kernel<<<(N_NODES * 16 + 255) / 256, 256, 0, stream>>>(y1, wa2, al);
  weights_kernel<<<aggBlocks, 256, 0, stream>>>(al, row_off, csr_src, ew, nsum);
  agg2_kernel<<<aggBlocks, 256, 0, stream>>>(y1, ew, nsum, row_off, csr_src, aggx);
  outgemm_kernel<<<(N_NODES + GR - 1) / GR, 256, 0, stream>>>(aggx, w2p, b2, y1, y2p);
  stats_kernel<<<waveBlocks, 256, 0, stream>>>(y2p, batch, gs2, gss2);
  finalize_kernel<<<1, 64, 0, stream>>>(gstart, gs2, gss2, mean2, rstd2);
  norm_relu_pool_kernel<<<waveBlocks, 256, 0, stream>>>(y2p, batch, mean2, rstd2, l2w, l2b, pooled);

  // ---- head ----
  head_kernel<<<(NG * 32 + 255) / 256, 256, 0, stream>>>(pooled, gstart, Wh, bh, out);
}

// Round 4
// 368.812 us; speedup vs baseline: 2.3581x; 1.2962x over previous
//
#include <hip/hip_runtime.h>
#include <math.h>

#define N_NODES 50000
#define N_EDGES 400000
#define E_TOT   (N_EDGES + N_NODES)
#define NG      64
#define NEG_SLOPE 0.2f

typedef __attribute__((ext_vector_type(8))) short bf16x8;
typedef __attribute__((ext_vector_type(4))) float f32x4;

// ---------------- helpers ----------------
__device__ __forceinline__ float wave_sum(float v){
#pragma unroll
  for (int off = 32; off; off >>= 1) v += __shfl_xor(v, off, 64);
  return v;
}
__device__ __forceinline__ float lrelu(float x){ return x > 0.f ? x : NEG_SLOPE * x; }
__device__ __forceinline__ ushort f2bf(float f){
  union { float f; unsigned u; } v; v.f = f;
  unsigned r = v.u + 0x7FFFu + ((v.u >> 16) & 1u);  // RNE
  return (ushort)(r >> 16);
}

// ---------------- prep: collapse attention vectors & permute W ----------------
__global__ void prep_wa_kernel(const float* __restrict__ W, const float* __restrict__ asrc,
                               const float* __restrict__ adst, float* __restrict__ wa){
  int idx = blockIdx.x * blockDim.x + threadIdx.x;
  if (idx >= 64 * 16) return;
  int k = idx >> 4, c = idx & 15;
  int h = c & 7;
  const float* a = (c < 8) ? asrc : adst;
  float s = 0.f;
#pragma unroll
  for (int d = 0; d < 64; ++d) s = fmaf(W[k * 512 + h * 64 + d], a[h * 64 + d], s);
  wa[idx] = s;
}

// wpT[j][i] = W[d][h*64+j]/8 as bf16, where i = h*64+d  (B^T for MFMA: [64 cols][512 k])
__global__ void prep_wpt_kernel(const float* __restrict__ W, ushort* __restrict__ wpT){
  int idx = blockIdx.x * blockDim.x + threadIdx.x;
  if (idx >= 64 * 512) return;
  int j = idx >> 9, i = idx & 511;
  int h = i >> 6, d = i & 63;
  wpT[idx] = f2bf(W[d * 512 + h * 64 + j] * 0.125f);
}

// ---------------- graph boundaries from sorted batch (NO atomics) ----------------
__global__ void graph_bounds_kernel(const int* __restrict__ batch, int* __restrict__ gstart){
  int n = blockIdx.x * blockDim.x + threadIdx.x;
  if (n > N_NODES) return;
  int g = (n < N_NODES) ? batch[n] : NG;
  if (n == 0){
    for (int gg = 0; gg <= g; ++gg) gstart[gg] = 0;
  } else {
    int gp = batch[n - 1];
    for (int gg = gp + 1; gg <= g; ++gg) gstart[gg] = n;
  }
}

// ---------------- CSR build (by dst), shared across both layers ----------------
__global__ void count_kernel(const int* __restrict__ ei, int* __restrict__ counts){
  int e = blockIdx.x * blockDim.x + threadIdx.x;
  if (e >= E_TOT) return;
  int dst = (e < N_EDGES) ? ei[N_EDGES + e] : (e - N_EDGES);
  atomicAdd(&counts[dst], 1);
}

#define SCAN_B 1024
#define SCAN_NB ((N_NODES + SCAN_B - 1) / SCAN_B)   // 49

__global__ __launch_bounds__(SCAN_B) void scan1_kernel(const int* __restrict__ counts,
                                                       int* __restrict__ row_off,
                                                       int* __restrict__ blocksum){
  __shared__ int sh[SCAN_B];
  int i = blockIdx.x * SCAN_B + threadIdx.x;
  int v = (i < N_NODES) ? counts[i] : 0;
  sh[threadIdx.x] = v;
  __syncthreads();
#pragma unroll
  for (int off = 1; off < SCAN_B; off <<= 1){
    int add = (threadIdx.x >= (unsigned)off) ? sh[threadIdx.x - off] : 0;
    __syncthreads();
    sh[threadIdx.x] += add;
    __syncthreads();
  }
  if (i < N_NODES) row_off[i] = sh[threadIdx.x] - v;
  if (threadIdx.x == SCAN_B - 1) blocksum[blockIdx.x] = sh[SCAN_B - 1];
}

__global__ void scan2_kernel(int* __restrict__ blocksum, int* __restrict__ blockoff){
  __shared__ int sh[64];
  int t = threadIdx.x;
  int v = (t < SCAN_NB) ? blocksum[t] : 0;
  sh[t] = v;
  __syncthreads();
#pragma unroll
  for (int off = 1; off < 64; off <<= 1){
    int add = (t >= off) ? sh[t - off] : 0;
    __syncthreads();
    sh[t] += add;
    __syncthreads();
  }
  if (t < SCAN_NB) blockoff[t] = sh[t] - v;
  if (t == 63) blockoff[SCAN_NB] = sh[63];
}

__global__ void scan3_kernel(int* __restrict__ row_off, const int* __restrict__ blockoff){
  int i = blockIdx.x * blockDim.x + threadIdx.x;
  if (i < N_NODES) row_off[i] += blockoff[i >> 10];
  if (i == 0) row_off[N_NODES] = blockoff[SCAN_NB];
}

__global__ void scatter_kernel(const int* __restrict__ ei, const int* __restrict__ row_off,
                               int* __restrict__ cursor, int* __restrict__ csr_src){
  int e = blockIdx.x * blockDim.x + threadIdx.x;
  if (e >= E_TOT) return;
  int src, dst;
  if (e < N_EDGES){ src = ei[e]; dst = ei[N_EDGES + e]; }
  else            { src = dst = e - N_EDGES; }
  int pos = row_off[dst] + atomicAdd(&cursor[dst], 1);
  csr_src[pos] = src;
}

// ---------------- al = xin @ Wa  ([N,64] @ [64,16]) ----------------
__global__ void al_kernel(const float* __restrict__ xin, const float* __restrict__ wa,
                          float* __restrict__ al){
  __shared__ float w[64 * 16];
  for (int i = threadIdx.x; i < 1024; i += blockDim.x) w[i] = wa[i];
  __syncthreads();
  int idx = blockIdx.x * blockDim.x + threadIdx.x;
  if (idx >= N_NODES * 16) return;
  int n = idx >> 4, c = idx & 15;
  const float* xr = xin + n * 64;
  float s = 0.f;
#pragma unroll
  for (int k = 0; k < 64; ++k) s = fmaf(xr[k], w[k * 16 + c], s);
  al[idx] = s;
}

// ---------------- softmax weights per (edge, head): lane-parallel ----------------
__global__ void weights_kernel(const float* __restrict__ al, const int* __restrict__ row_off,
                               const int* __restrict__ csr_src, float* __restrict__ ew,
                               float* __restrict__ nsum){
  int wid = (int)((blockIdx.x * blockDim.x + threadIdx.x) >> 6);
  int lane = threadIdx.x & 63;
  if (wid >= N_NODES) return;
  const int n = wid;
  const int eo = lane >> 3, h = lane & 7;
  const int s0 = row_off[n], s1 = row_off[n + 1];
  const float ald = al[n * 16 + 8 + h];

  float m = -1e30f;
  for (int e = s0 + eo; e < s1; e += 8){
    int s = csr_src[e];
    m = fmaxf(m, lrelu(al[s * 16 + h] + ald));
  }
#pragma unroll
  for (int off = 8; off < 64; off <<= 1) m = fmaxf(m, __shfl_xor(m, off, 64));

  float sum = 0.f;
  for (int e = s0 + eo; e < s1; e += 8){
    int s = csr_src[e];
    float l = lrelu(al[s * 16 + h] + ald);
    float w = __expf(l - m);
    sum += w;
    ew[(size_t)e * 8 + h] = w;
  }
#pragma unroll
  for (int off = 8; off < 64; off <<= 1) sum += __shfl_xor(sum, off, 64);
  if (lane < 8) nsum[n * 8 + lane] = sum;
}

// ---------------- aggregation: wave per node, lane = dim; bf16 output ----------------
__global__ void agg2_kernel(const float* __restrict__ xin, const float* __restrict__ ew,
                            const float* __restrict__ nsum, const int* __restrict__ row_off,
                            const int* __restrict__ csr_src, ushort* __restrict__ aggx){
  int wid = (int)((blockIdx.x * blockDim.x + threadIdx.x) >> 6);
  int lane = threadIdx.x & 63;
  if (wid >= N_NODES) return;
  const int n = wid;
  const int s0 = row_off[n], s1 = row_off[n + 1];
  float acc[8];
#pragma unroll
  for (int h = 0; h < 8; ++h) acc[h] = 0.f;

  for (int e = s0; e < s1; ++e){
    int s = csr_src[e];
    float xv = xin[s * 64 + lane];
    float4 w0 = *(const float4*)(ew + (size_t)e * 8);
    float4 w1 = *(const float4*)(ew + (size_t)e * 8 + 4);
    acc[0] = fmaf(w0.x, xv, acc[0]);
    acc[1] = fmaf(w0.y, xv, acc[1]);
    acc[2] = fmaf(w0.z, xv, acc[2]);
    acc[3] = fmaf(w0.w, xv, acc[3]);
    acc[4] = fmaf(w1.x, xv, acc[4]);
    acc[5] = fmaf(w1.y, xv, acc[5]);
    acc[6] = fmaf(w1.z, xv, acc[6]);
    acc[7] = fmaf(w1.w, xv, acc[7]);
  }
#pragma unroll
  for (int h = 0; h < 8; ++h)
    aggx[(size_t)n * 512 + h * 64 + lane] = f2bf(acc[h] / (nsum[n * 8 + h] + 1e-16f));
}

// ---------------- Y = aggx(bf16) @ W'(bf16) + bias + res via MFMA ----------------
// block: 64 rows, 4 waves; wave w -> rows w*16..w*16+15, all 64 cols (4 col-tiles)
__global__ __launch_bounds__(256) void outgemm_mfma_kernel(const ushort* __restrict__ A,
                                                           const ushort* __restrict__ BT,
                                                           const float* __restrict__ bias,
                                                           const float* __restrict__ res,
                                                           float* __restrict__ Y){
  __shared__ ushort Al[64][136];  // +8 pad: 272B row stride -> 2-way bank alias (free)
  __shared__ ushort Bl[64][136];
  const int t = threadIdx.x;
  const int wave = t >> 6, lane = t & 63;
  const int rowbase = blockIdx.x * 64;
  const int frow = lane & 15, kc = lane >> 4;
  f32x4 acc[4];
#pragma unroll
  for (int ct = 0; ct < 4; ++ct) acc[ct] = (f32x4){0.f, 0.f, 0.f, 0.f};

  for (int k0 = 0; k0 < 512; k0 += 128){
    // stage A (64x128 bf16) and B^T (64x128 bf16); 16B per thread per pass
#pragma unroll
    for (int ppass = 0; ppass < 4; ++ppass){
      int idx = (ppass * 256 + t) * 8;
      int r = idx >> 7, k = idx & 127;
      int grow = rowbase + r;
      uint4 v = make_uint4(0u, 0u, 0u, 0u);
      if (grow < N_NODES) v = *(const uint4*)(A + (size_t)grow * 512 + k0 + k);
      *(uint4*)&Al[r][k] = v;
      uint4 w = *(const uint4*)(BT + (size_t)r * 512 + k0 + k);
      *(uint4*)&Bl[r][k] = w;
    }
    __syncthreads();
#pragma unroll
    for (int kf = 0; kf < 4; ++kf){
      bf16x8 a = *(const bf16x8*)&Al[wave * 16 + frow][kf * 32 + kc * 8];
#pragma unroll
      for (int ct = 0; ct < 4; ++ct){
        bf16x8 b = *(const bf16x8*)&Bl[ct * 16 + frow][kf * 32 + kc * 8];
        acc[ct] = __builtin_amdgcn_mfma_f32_16x16x32_bf16(a, b, acc[ct], 0, 0, 0);
      }
    }
    __syncthreads();
  }
  // epilogue: D mapping col=lane&15, row=(lane>>4)*4+reg
  const int col0 = lane & 15, rsub = (lane >> 4) * 4;
#pragma unroll
  for (int ct = 0; ct < 4; ++ct){
    int col = ct * 16 + col0;
    float bs = bias[col];
#pragma unroll
    for (int j = 0; j < 4; ++j){
      int grow = rowbase + wave * 16 + rsub + j;
      if (grow < N_NODES)
        Y[(size_t)grow * 64 + col] = acc[ct][j] + bs + res[(size_t)grow * 64 + col];
    }
  }
}

// ---------------- graph-LN stats ----------------
__global__ void stats_kernel(const float* __restrict__ Y, const int* __restrict__ batch,
                             float* __restrict__ gs, float* __restrict__ gss){
  int w = (int)((blockIdx.x * blockDim.x + threadIdx.x) >> 6);
  int lane = threadIdx.x & 63;
  int nbase = w * 16;
  if (nbase >= N_NODES) return;
  int nend = min(nbase + 16, N_NODES);
  float s = 0.f, ss = 0.f;
  int g = batch[nbase];
  for (int n = nbase; n < nend; ++n){
    int gn = batch[n];
    if (gn != g){
      float rs = wave_sum(s), rss = wave_sum(ss);
      if (lane == 0){ atomicAdd(&gs[g], rs); atomicAdd(&gss[g], rss); }
      s = 0.f; ss = 0.f; g = gn;
    }
    float v = Y[(size_t)n * 64 + lane];
    s += v; ss = fmaf(v, v, ss);
  }
  float rs = wave_sum(s), rss = wave_sum(ss);
  if (lane == 0){ atomicAdd(&gs[g], rs); atomicAdd(&gss[g], rss); }
}

__global__ void finalize_kernel(const int* __restrict__ gstart, const float* __restrict__ gs,
                                const float* __restrict__ gss, float* __restrict__ mean,
                                float* __restrict__ rstd){
  int g = threadIdx.x;
  if (g >= NG) return;
  float cnt = (float)(gstart[g + 1] - gstart[g]);
  float norm = fmaxf(cnt, 1.f) * 64.f;
  float m = gs[g] / norm;
  float var = fmaxf(gss[g] / norm - m * m, 0.f);
  mean[g] = m;
  rstd[g] = rsqrtf(var + 1e-5f);
}

// ---------------- normalize + relu (layer 1) ----------------
__global__ void norm_relu_kernel(const float* __restrict__ Y, const int* __restrict__ batch,
                                 const float* __restrict__ mean, const float* __restrict__ rstd,
                                 const float* __restrict__ lw, const float* __restrict__ lb,
                                 float* __restrict__ out){
  int idx = blockIdx.x * blockDim.x + threadIdx.x;
  if (idx >= N_NODES * 64) return;
  int n = idx >> 6, c = idx & 63;
  int g = batch[n];
  float v = (Y[idx] - mean[g]) * rstd[g] * lw[c] + lb[c];
  out[idx] = fmaxf(v, 0.f);
}

// ---------------- normalize + relu + pooled accumulation (layer 2) ----------------
__global__ void norm_relu_pool_kernel(const float* __restrict__ Y, const int* __restrict__ batch,
                                      const float* __restrict__ mean, const float* __restrict__ rstd,
                                      const float* __restrict__ lw, const float* __restrict__ lb,
                                      float* __restrict__ pooled){
  int w = (int)((blockIdx.x * blockDim.x + threadIdx.x) >> 6);
  int lane = threadIdx.x & 63;
  int nbase = w * 16;
  if (nbase >= N_NODES) return;
  int nend = min(nbase + 16, N_NODES);
  float accv = 0.f;
  int g = batch[nbase];
  for (int n = nbase; n < nend; ++n){
    int gn = batch[n];
    if (gn != g){
      atomicAdd(&pooled[g * 64 + lane], accv);
      accv = 0.f; g = gn;
    }
    float v = (Y[(size_t)n * 64 + lane] - mean[g]) * rstd[g] * lw[lane] + lb[lane];
    accv += fmaxf(v, 0.f);
  }
  atomicAdd(&pooled[g * 64 + lane], accv);
}

// ---------------- head ----------------
__global__ void head_kernel(const float* __restrict__ pooled, const int* __restrict__ gstart,
                            const float* __restrict__ Wh, const float* __restrict__ bh,
                            float* __restrict__ out){
  int idx = blockIdx.x * blockDim.x + threadIdx.x;
  if (idx >= NG * 32) return;
  int g = idx >> 5, o = idx & 31;
  float cnt = (float)(gstart[g + 1] - gstart[g]);
  float inv = 1.f / fmaxf(cnt, 1.f);
  float s = 0.f;
#pragma unroll
  for (int d = 0; d < 64; ++d) s = fmaf(pooled[g * 64 + d] * inv, Wh[d * 32 + o], s);
  out[idx] = fmaxf(s + bh[o], 0.f);
}

// ---------------- launch ----------------
extern "C" void kernel_launch(void* const* d_in, const int* in_sizes, int n_in,
                              void* d_out, int out_size, void* d_ws, size_t ws_size,
                              hipStream_t stream){
  const float* x     = (const float*)d_in[0];
  const int*   ei    = (const int*)d_in[1];
  const int*   batch = (const int*)d_in[2];
  const float* W1    = (const float*)d_in[3];
  const float* as1   = (const float*)d_in[4];
  const float* ad1   = (const float*)d_in[5];
  const float* b1    = (const float*)d_in[6];
  const float* l1w   = (const float*)d_in[7];
  const float* l1b   = (const float*)d_in[8];
  const float* W2    = (const float*)d_in[9];
  const float* as2   = (const float*)d_in[10];
  const float* ad2   = (const float*)d_in[11];
  const float* b2    = (const float*)d_in[12];
  const float* l2w   = (const float*)d_in[13];
  const float* l2b   = (const float*)d_in[14];
  const float* Wh    = (const float*)d_in[15];
  const float* bh    = (const float*)d_in[16];
  float* out = (float*)d_out;

  char* p = (char*)d_ws;
  auto alloc = [&](size_t bytes) -> void* {
    void* r = (void*)p;
    p += (bytes + 255) & ~(size_t)255;
    return r;
  };
  int*    counts   = (int*)alloc(N_NODES * 4);
  int*    row_off  = (int*)alloc((N_NODES + 1) * 4);
  int*    cursor   = (int*)alloc(N_NODES * 4);
  int*    csr_src  = (int*)alloc(E_TOT * 4);
  int*    gstart   = (int*)alloc((NG + 1) * 4);
  int*    blocksum = (int*)alloc((SCAN_NB + 1) * 4);
  int*    blockoff = (int*)alloc((SCAN_NB + 1) * 4);
  float*  wa1      = (float*)alloc(64 * 16 * 4);
  float*  wa2      = (float*)alloc(64 * 16 * 4);
  ushort* w1pT     = (ushort*)alloc(64 * 512 * 2);
  ushort* w2pT     = (ushort*)alloc(64 * 512 * 2);
  float*  al       = (float*)alloc((size_t)N_NODES * 16 * 4);
  float*  ew       = (float*)alloc((size_t)E_TOT * 8 * 4);
  float*  nsum     = (float*)alloc((size_t)N_NODES * 8 * 4);
  ushort* aggx     = (ushort*)alloc((size_t)N_NODES * 512 * 2);
  float*  y1p      = (float*)alloc((size_t)N_NODES * 64 * 4);
  float*  y1       = (float*)alloc((size_t)N_NODES * 64 * 4);
  float*  y2p      = y1p;  // y1p dead after layer-1 norm_relu
  float*  gstats   = (float*)alloc(8 * NG * 4);
  float*  pooled   = (float*)alloc(NG * 64 * 4);
  float* gs1 = gstats, *gss1 = gstats + NG, *gs2 = gstats + 2*NG, *gss2 = gstats + 3*NG;
  float* mean1 = gstats + 4*NG, *rstd1 = gstats + 5*NG, *mean2 = gstats + 6*NG, *rstd2 = gstats + 7*NG;

  hipMemsetAsync(counts, 0, N_NODES * 4, stream);
  hipMemsetAsync(cursor, 0, N_NODES * 4, stream);
  hipMemsetAsync(gstats, 0, 8 * NG * 4, stream);
  hipMemsetAsync(pooled, 0, NG * 64 * 4, stream);

  // prep
  prep_wa_kernel<<<4, 256, 0, stream>>>(W1, as1, ad1, wa1);
  prep_wa_kernel<<<4, 256, 0, stream>>>(W2, as2, ad2, wa2);
  prep_wpt_kernel<<<128, 256, 0, stream>>>(W1, w1pT);
  prep_wpt_kernel<<<128, 256, 0, stream>>>(W2, w2pT);

  // graph bounds (no atomics — batch is sorted)
  graph_bounds_kernel<<<(N_NODES + 256) / 256, 256, 0, stream>>>(batch, gstart);

  // CSR
  count_kernel<<<(E_TOT + 255) / 256, 256, 0, stream>>>(ei, counts);
  scan1_kernel<<<SCAN_NB, SCAN_B, 0, stream>>>(counts, row_off, blocksum);
  scan2_kernel<<<1, 64, 0, stream>>>(blocksum, blockoff);
  scan3_kernel<<<(N_NODES + 255) / 256, 256, 0, stream>>>(row_off, blockoff);
  scatter_kernel<<<(E_TOT + 255) / 256, 256, 0, stream>>>(ei, row_off, cursor, csr_src);

  const int aggBlocks  = (N_NODES + 3) / 4;
  const int waveBlocks = ((N_NODES + 15) / 16 * 64 + 255) / 256;
  const int gemmBlocks = (N_NODES + 63) / 64;

  // ---- layer 1 ----
  al_kernel<<<(N_NODES * 16 + 255) / 256, 256, 0, stream>>>(x, wa1, al);
  weights_kernel<<<aggBlocks, 256, 0, stream>>>(al, row_off, csr_src, ew, nsum);
  agg2_kernel<<<aggBlocks, 256, 0, stream>>>(x, ew, nsum, row_off, csr_src, aggx);
  outgemm_mfma_kernel<<<gemmBlocks, 256, 0, stream>>>(aggx, w1pT, b1, x, y1p);
  stats_kernel<<<waveBlocks, 256, 0, stream>>>(y1p, batch, gs1, gss1);
  finalize_kernel<<<1, 64, 0, stream>>>(gstart, gs1, gss1, mean1, rstd1);
  norm_relu_kernel<<<(N_NODES * 64 + 255) / 256, 256, 0, stream>>>(y1p, batch, mean1, rstd1, l1w, l1b, y1);

  // ---- layer 2 ----
  al_kernel<<<(N_NODES * 16 + 255) / 256, 256, 0, stream>>>(y1, wa2, al);
  weights_kernel<<<aggBlocks, 256, 0, stream>>>(al, row_off, csr_src, ew, nsum);
  agg2_kernel<<<aggBlocks, 256, 0, stream>>>(y1, ew, nsum, row_off, csr_src, aggx);
  outgemm_mfma_kernel<<<gemmBlocks, 256, 0, stream>>>(aggx, w2pT, b2, y1, y2p);
  stats_kernel<<<waveBlocks, 256, 0, stream>>>(y2p, batch, gs2, gss2);
  finalize_kernel<<<1, 64, 0, stream>>>(gstart, gs2, gss2, mean2, rstd2);
  norm_relu_pool_kernel<<<waveBlocks, 256, 0, stream>>>(y2p, batch, mean2, rstd2, l2w, l2b, pooled);

  // ---- head ----
  head_kernel<<<(NG * 32 + 255) / 256, 256, 0, stream>>>(pooled, gstart, Wh, bh, out);
}

// Round 5
// 323.134 us; speedup vs baseline: 2.6914x; 1.1414x over previous
//
#include <hip/hip_runtime.h>
#include <math.h>

#define N_NODES 50000
#define N_EDGES 400000
#define E_TOT   (N_EDGES + N_NODES)
#define NG      64
#define NEG_SLOPE 0.2f

typedef __attribute__((ext_vector_type(8))) short bf16x8;
typedef __attribute__((ext_vector_type(4))) float f32x4;

// ---------------- helpers ----------------
__device__ __forceinline__ float wave_sum(float v){
#pragma unroll
  for (int off = 32; off; off >>= 1) v += __shfl_xor(v, off, 64);
  return v;
}
__device__ __forceinline__ float lrelu(float x){ return x > 0.f ? x : NEG_SLOPE * x; }
__device__ __forceinline__ ushort f2bf(float f){
  union { float f; unsigned u; } v; v.f = f;
  unsigned r = v.u + 0x7FFFu + ((v.u >> 16) & 1u);  // RNE
  return (ushort)(r >> 16);
}
__device__ __forceinline__ float bf2f(ushort u){
  return __uint_as_float(((unsigned)u) << 16);
}
__device__ __forceinline__ float bflo(unsigned u){ return __uint_as_float(u << 16); }
__device__ __forceinline__ float bfhi(unsigned u){ return __uint_as_float(u & 0xffff0000u); }

// ---------------- f32 -> bf16 bulk convert (8 elems/thread) ----------------
__global__ void tobf_kernel(const float* __restrict__ in, ushort* __restrict__ out){
  int i = blockIdx.x * blockDim.x + threadIdx.x;
  if (i >= N_NODES * 64 / 8) return;
  float4 a = *(const float4*)(in + (size_t)i * 8);
  float4 b = *(const float4*)(in + (size_t)i * 8 + 4);
  ushort o[8] = {f2bf(a.x), f2bf(a.y), f2bf(a.z), f2bf(a.w),
                 f2bf(b.x), f2bf(b.y), f2bf(b.z), f2bf(b.w)};
  *(uint4*)(out + (size_t)i * 8) = *(const uint4*)o;
}

// ---------------- prep: collapse attention vectors & permute W ----------------
__global__ void prep_wa_kernel(const float* __restrict__ W, const float* __restrict__ asrc,
                               const float* __restrict__ adst, float* __restrict__ wa){
  int idx = blockIdx.x * blockDim.x + threadIdx.x;
  if (idx >= 64 * 16) return;
  int k = idx >> 4, c = idx & 15;
  int h = c & 7;
  const float* a = (c < 8) ? asrc : adst;
  float s = 0.f;
#pragma unroll
  for (int d = 0; d < 64; ++d) s = fmaf(W[k * 512 + h * 64 + d], a[h * 64 + d], s);
  wa[idx] = s;
}

// wpT[j][i] = W[d][h*64+j]/8 as bf16, where i = h*64+d  (B^T for MFMA: [64 cols][512 k])
__global__ void prep_wpt_kernel(const float* __restrict__ W, ushort* __restrict__ wpT){
  int idx = blockIdx.x * blockDim.x + threadIdx.x;
  if (idx >= 64 * 512) return;
  int j = idx >> 9, i = idx & 511;
  int h = i >> 6, d = i & 63;
  wpT[idx] = f2bf(W[d * 512 + h * 64 + j] * 0.125f);
}

// ---------------- graph boundaries from sorted batch (NO atomics) ----------------
__global__ void graph_bounds_kernel(const int* __restrict__ batch, int* __restrict__ gstart){
  int n = blockIdx.x * blockDim.x + threadIdx.x;
  if (n > N_NODES) return;
  int g = (n < N_NODES) ? batch[n] : NG;
  if (n == 0){
    for (int gg = 0; gg <= g; ++gg) gstart[gg] = 0;
  } else {
    int gp = batch[n - 1];
    for (int gg = gp + 1; gg <= g; ++gg) gstart[gg] = n;
  }
}

// ---------------- CSR build (by dst), shared across both layers ----------------
__global__ void count_kernel(const int* __restrict__ ei, int* __restrict__ counts){
  int e = blockIdx.x * blockDim.x + threadIdx.x;
  if (e >= E_TOT) return;
  int dst = (e < N_EDGES) ? ei[N_EDGES + e] : (e - N_EDGES);
  atomicAdd(&counts[dst], 1);
}

#define SCAN_B 1024
#define SCAN_NB ((N_NODES + SCAN_B - 1) / SCAN_B)   // 49

__global__ __launch_bounds__(SCAN_B) void scan1_kernel(const int* __restrict__ counts,
                                                       int* __restrict__ row_off,
                                                       int* __restrict__ blocksum){
  __shared__ int sh[SCAN_B];
  int i = blockIdx.x * SCAN_B + threadIdx.x;
  int v = (i < N_NODES) ? counts[i] : 0;
  sh[threadIdx.x] = v;
  __syncthreads();
#pragma unroll
  for (int off = 1; off < SCAN_B; off <<= 1){
    int add = (threadIdx.x >= (unsigned)off) ? sh[threadIdx.x - off] : 0;
    __syncthreads();
    sh[threadIdx.x] += add;
    __syncthreads();
  }
  if (i < N_NODES) row_off[i] = sh[threadIdx.x] - v;
  if (threadIdx.x == SCAN_B - 1) blocksum[blockIdx.x] = sh[SCAN_B - 1];
}

__global__ void scan2_kernel(int* __restrict__ blocksum, int* __restrict__ blockoff){
  __shared__ int sh[64];
  int t = threadIdx.x;
  int v = (t < SCAN_NB) ? blocksum[t] : 0;
  sh[t] = v;
  __syncthreads();
#pragma unroll
  for (int off = 1; off < 64; off <<= 1){
    int add = (t >= off) ? sh[t - off] : 0;
    __syncthreads();
    sh[t] += add;
    __syncthreads();
  }
  if (t < SCAN_NB) blockoff[t] = sh[t] - v;
  if (t == 63) blockoff[SCAN_NB] = sh[63];
}

__global__ void scan3_kernel(int* __restrict__ row_off, const int* __restrict__ blockoff){
  int i = blockIdx.x * blockDim.x + threadIdx.x;
  if (i < N_NODES) row_off[i] += blockoff[i >> 10];
  if (i == 0) row_off[N_NODES] = blockoff[SCAN_NB];
}

__global__ void scatter_kernel(const int* __restrict__ ei, const int* __restrict__ row_off,
                               int* __restrict__ cursor, int* __restrict__ csr_src){
  int e = blockIdx.x * blockDim.x + threadIdx.x;
  if (e >= E_TOT) return;
  int src, dst;
  if (e < N_EDGES){ src = ei[e]; dst = ei[N_EDGES + e]; }
  else            { src = dst = e - N_EDGES; }
  int pos = row_off[dst] + atomicAdd(&cursor[dst], 1);
  csr_src[pos] = src;
}

// ---------------- al = xin(bf16) @ Wa  ([N,64] @ [64,16]) ----------------
__global__ void al_kernel(const ushort* __restrict__ xin, const float* __restrict__ wa,
                          float* __restrict__ al){
  __shared__ float w[64 * 16];
  for (int i = threadIdx.x; i < 1024; i += blockDim.x) w[i] = wa[i];
  __syncthreads();
  int idx = blockIdx.x * blockDim.x + threadIdx.x;
  if (idx >= N_NODES * 16) return;
  int n = idx >> 4, c = idx & 15;
  const ushort* xr = xin + (size_t)n * 64;
  float s = 0.f;
#pragma unroll
  for (int k8 = 0; k8 < 8; ++k8){
    uint4 u = *(const uint4*)(xr + k8 * 8);
    unsigned uu[4] = {u.x, u.y, u.z, u.w};
#pragma unroll
    for (int j = 0; j < 4; ++j){
      int k = k8 * 8 + j * 2;
      s = fmaf(bflo(uu[j]), w[k * 16 + c], s);
      s = fmaf(bfhi(uu[j]), w[(k + 1) * 16 + c], s);
    }
  }
  al[idx] = s;
}

// ---------------- normalized softmax weights -> bf16 (no max-sub; logits bounded) ----------------
// wave per node; lane = eo*8 + h
__global__ void weights_kernel(const float* __restrict__ al, const int* __restrict__ row_off,
                               const int* __restrict__ csr_src, ushort* __restrict__ ewb){
  int wid = (int)((blockIdx.x * blockDim.x + threadIdx.x) >> 6);
  int lane = threadIdx.x & 63;
  if (wid >= N_NODES) return;
  const int n = wid;
  const int eo = lane >> 3, h = lane & 7;
  const int s0 = row_off[n], s1 = row_off[n + 1];
  const float ald = al[n * 16 + 8 + h];

  float sum = 0.f;
  for (int e = s0 + eo; e < s1; e += 8){
    int s = csr_src[e];
    sum += __expf(lrelu(al[s * 16 + h] + ald));
  }
#pragma unroll
  for (int off = 8; off < 64; off <<= 1) sum += __shfl_xor(sum, off, 64);
  float inv = 1.f / (sum + 1e-16f);

  for (int e = s0 + eo; e < s1; e += 8){
    int s = csr_src[e];
    float w = __expf(lrelu(al[s * 16 + h] + ald)) * inv;
    ewb[(size_t)e * 8 + h] = f2bf(w);
  }
}

// ---------------- aggregation: wave per node, lane = dim; bf16 in/out ----------------
__global__ void agg2_kernel(const ushort* __restrict__ xb, const ushort* __restrict__ ewb,
                            const int* __restrict__ row_off, const int* __restrict__ csr_src,
                            ushort* __restrict__ aggx){
  int wid = (int)((blockIdx.x * blockDim.x + threadIdx.x) >> 6);
  int lane = threadIdx.x & 63;
  if (wid >= N_NODES) return;
  const int n = wid;
  const int s0 = row_off[n], s1 = row_off[n + 1];
  float acc[8];
#pragma unroll
  for (int h = 0; h < 8; ++h) acc[h] = 0.f;

  int e = s0;
  for (; e + 2 <= s1; e += 2){
    int sa = csr_src[e], sb = csr_src[e + 1];
    float xa = bf2f(xb[(size_t)sa * 64 + lane]);
    float xc = bf2f(xb[(size_t)sb * 64 + lane]);
    uint4 wa = *(const uint4*)(ewb + (size_t)e * 8);
    uint4 wb = *(const uint4*)(ewb + (size_t)(e + 1) * 8);
    acc[0] = fmaf(bflo(wa.x), xa, acc[0]);
    acc[1] = fmaf(bfhi(wa.x), xa, acc[1]);
    acc[2] = fmaf(bflo(wa.y), xa, acc[2]);
    acc[3] = fmaf(bfhi(wa.y), xa, acc[3]);
    acc[4] = fmaf(bflo(wa.z), xa, acc[4]);
    acc[5] = fmaf(bfhi(wa.z), xa, acc[5]);
    acc[6] = fmaf(bflo(wa.w), xa, acc[6]);
    acc[7] = fmaf(bfhi(wa.w), xa, acc[7]);
    acc[0] = fmaf(bflo(wb.x), xc, acc[0]);
    acc[1] = fmaf(bfhi(wb.x), xc, acc[1]);
    acc[2] = fmaf(bflo(wb.y), xc, acc[2]);
    acc[3] = fmaf(bfhi(wb.y), xc, acc[3]);
    acc[4] = fmaf(bflo(wb.z), xc, acc[4]);
    acc[5] = fmaf(bfhi(wb.z), xc, acc[5]);
    acc[6] = fmaf(bflo(wb.w), xc, acc[6]);
    acc[7] = fmaf(bfhi(wb.w), xc, acc[7]);
  }
  if (e < s1){
    int sa = csr_src[e];
    float xa = bf2f(xb[(size_t)sa * 64 + lane]);
    uint4 wa = *(const uint4*)(ewb + (size_t)e * 8);
    acc[0] = fmaf(bflo(wa.x), xa, acc[0]);
    acc[1] = fmaf(bfhi(wa.x), xa, acc[1]);
    acc[2] = fmaf(bflo(wa.y), xa, acc[2]);
    acc[3] = fmaf(bfhi(wa.y), xa, acc[3]);
    acc[4] = fmaf(bflo(wa.z), xa, acc[4]);
    acc[5] = fmaf(bfhi(wa.z), xa, acc[5]);
    acc[6] = fmaf(bflo(wa.w), xa, acc[6]);
    acc[7] = fmaf(bfhi(wa.w), xa, acc[7]);
  }
#pragma unroll
  for (int h = 0; h < 8; ++h)
    aggx[(size_t)n * 512 + h * 64 + lane] = f2bf(acc[h]);
}

// ---------------- Y = aggx(bf16) @ W'(bf16) + bias + res via MFMA ----------------
__global__ __launch_bounds__(256) void outgemm_mfma_kernel(const ushort* __restrict__ A,
                                                           const ushort* __restrict__ BT,
                                                           const float* __restrict__ bias,
                                                           const float* __restrict__ res,
                                                           float* __restrict__ Y){
  __shared__ ushort Al[64][136];  // +8 pad
  __shared__ ushort Bl[64][136];
  const int t = threadIdx.x;
  const int wave = t >> 6, lane = t & 63;
  const int rowbase = blockIdx.x * 64;
  const int frow = lane & 15, kc = lane >> 4;
  f32x4 acc[4];
#pragma unroll
  for (int ct = 0; ct < 4; ++ct) acc[ct] = (f32x4){0.f, 0.f, 0.f, 0.f};

  for (int k0 = 0; k0 < 512; k0 += 128){
#pragma unroll
    for (int ppass = 0; ppass < 4; ++ppass){
      int idx = (ppass * 256 + t) * 8;
      int r = idx >> 7, k = idx & 127;
      int grow = rowbase + r;
      uint4 v = make_uint4(0u, 0u, 0u, 0u);
      if (grow < N_NODES) v = *(const uint4*)(A + (size_t)grow * 512 + k0 + k);
      *(uint4*)&Al[r][k] = v;
      uint4 w = *(const uint4*)(BT + (size_t)r * 512 + k0 + k);
      *(uint4*)&Bl[r][k] = w;
    }
    __syncthreads();
#pragma unroll
    for (int kf = 0; kf < 4; ++kf){
      bf16x8 a = *(const bf16x8*)&Al[wave * 16 + frow][kf * 32 + kc * 8];
#pragma unroll
      for (int ct = 0; ct < 4; ++ct){
        bf16x8 b = *(const bf16x8*)&Bl[ct * 16 + frow][kf * 32 + kc * 8];
        acc[ct] = __builtin_amdgcn_mfma_f32_16x16x32_bf16(a, b, acc[ct], 0, 0, 0);
      }
    }
    __syncthreads();
  }
  const int col0 = lane & 15, rsub = (lane >> 4) * 4;
#pragma unroll
  for (int ct = 0; ct < 4; ++ct){
    int col = ct * 16 + col0;
    float bs = bias[col];
#pragma unroll
    for (int j = 0; j < 4; ++j){
      int grow = rowbase + wave * 16 + rsub + j;
      if (grow < N_NODES)
        Y[(size_t)grow * 64 + col] = acc[ct][j] + bs + res[(size_t)grow * 64 + col];
    }
  }
}

// ---------------- graph-LN stats ----------------
__global__ void stats_kernel(const float* __restrict__ Y, const int* __restrict__ batch,
                             float* __restrict__ gs, float* __restrict__ gss){
  int w = (int)((blockIdx.x * blockDim.x + threadIdx.x) >> 6);
  int lane = threadIdx.x & 63;
  int nbase = w * 16;
  if (nbase >= N_NODES) return;
  int nend = min(nbase + 16, N_NODES);
  float s = 0.f, ss = 0.f;
  int g = batch[nbase];
  for (int n = nbase; n < nend; ++n){
    int gn = batch[n];
    if (gn != g){
      float rs = wave_sum(s), rss = wave_sum(ss);
      if (lane == 0){ atomicAdd(&gs[g], rs); atomicAdd(&gss[g], rss); }
      s = 0.f; ss = 0.f; g = gn;
    }
    float v = Y[(size_t)n * 64 + lane];
    s += v; ss = fmaf(v, v, ss);
  }
  float rs = wave_sum(s), rss = wave_sum(ss);
  if (lane == 0){ atomicAdd(&gs[g], rs); atomicAdd(&gss[g], rss); }
}

__global__ void finalize_kernel(const int* __restrict__ gstart, const float* __restrict__ gs,
                                const float* __restrict__ gss, float* __restrict__ mean,
                                float* __restrict__ rstd){
  int g = threadIdx.x;
  if (g >= NG) return;
  float cnt = (float)(gstart[g + 1] - gstart[g]);
  float norm = fmaxf(cnt, 1.f) * 64.f;
  float m = gs[g] / norm;
  float var = fmaxf(gss[g] / norm - m * m, 0.f);
  mean[g] = m;
  rstd[g] = rsqrtf(var + 1e-5f);
}

// ---------------- normalize + relu (layer 1): f32 + bf16 outputs ----------------
__global__ void norm_relu_kernel(const float* __restrict__ Y, const int* __restrict__ batch,
                                 const float* __restrict__ mean, const float* __restrict__ rstd,
                                 const float* __restrict__ lw, const float* __restrict__ lb,
                                 float* __restrict__ out, ushort* __restrict__ outb){
  int idx = blockIdx.x * blockDim.x + threadIdx.x;
  if (idx >= N_NODES * 64) return;
  int n = idx >> 6, c = idx & 63;
  int g = batch[n];
  float v = (Y[idx] - mean[g]) * rstd[g] * lw[c] + lb[c];
  float r = fmaxf(v, 0.f);
  out[idx] = r;
  outb[idx] = f2bf(r);
}

// ---------------- normalize + relu + pooled accumulation (layer 2) ----------------
__global__ void norm_relu_pool_kernel(const float* __restrict__ Y, const int* __restrict__ batch,
                                      const float* __restrict__ mean, const float* __restrict__ rstd,
                                      const float* __restrict__ lw, const float* __restrict__ lb,
                                      float* __restrict__ pooled){
  int w = (int)((blockIdx.x * blockDim.x + threadIdx.x) >> 6);
  int lane = threadIdx.x & 63;
  int nbase = w * 16;
  if (nbase >= N_NODES) return;
  int nend = min(nbase + 16, N_NODES);
  float accv = 0.f;
  int g = batch[nbase];
  for (int n = nbase; n < nend; ++n){
    int gn = batch[n];
    if (gn != g){
      atomicAdd(&pooled[g * 64 + lane], accv);
      accv = 0.f; g = gn;
    }
    float v = (Y[(size_t)n * 64 + lane] - mean[g]) * rstd[g] * lw[lane] + lb[lane];
    accv += fmaxf(v, 0.f);
  }
  atomicAdd(&pooled[g * 64 + lane], accv);
}

// ---------------- head ----------------
__global__ void head_kernel(const float* __restrict__ pooled, const int* __restrict__ gstart,
                            const float* __restrict__ Wh, const float* __restrict__ bh,
                            float* __restrict__ out){
  int idx = blockIdx.x * blockDim.x + threadIdx.x;
  if (idx >= NG * 32) return;
  int g = idx >> 5, o = idx & 31;
  float cnt = (float)(gstart[g + 1] - gstart[g]);
  float inv = 1.f / fmaxf(cnt, 1.f);
  float s = 0.f;
#pragma unroll
  for (int d = 0; d < 64; ++d) s = fmaf(pooled[g * 64 + d] * inv, Wh[d * 32 + o], s);
  out[idx] = fmaxf(s + bh[o], 0.f);
}

// ---------------- launch ----------------
extern "C" void kernel_launch(void* const* d_in, const int* in_sizes, int n_in,
                              void* d_out, int out_size, void* d_ws, size_t ws_size,
                              hipStream_t stream){
  const float* x     = (const float*)d_in[0];
  const int*   ei    = (const int*)d_in[1];
  const int*   batch = (const int*)d_in[2];
  const float* W1    = (const float*)d_in[3];
  const float* as1   = (const float*)d_in[4];
  const float* ad1   = (const float*)d_in[5];
  const float* b1    = (const float*)d_in[6];
  const float* l1w   = (const float*)d_in[7];
  const float* l1b   = (const float*)d_in[8];
  const float* W2    = (const float*)d_in[9];
  const float* as2   = (const float*)d_in[10];
  const float* ad2   = (const float*)d_in[11];
  const float* b2    = (const float*)d_in[12];
  const float* l2w   = (const float*)d_in[13];
  const float* l2b   = (const float*)d_in[14];
  const float* Wh    = (const float*)d_in[15];
  const float* bh    = (const float*)d_in[16];
  float* out = (float*)d_out;

  char* p = (char*)d_ws;
  auto alloc = [&](size_t bytes) -> void* {
    void* r = (void*)p;
    p += (bytes + 255) & ~(size_t)255;
    return r;
  };
  int*    counts   = (int*)alloc(N_NODES * 4);
  int*    row_off  = (int*)alloc((N_NODES + 1) * 4);
  int*    cursor   = (int*)alloc(N_NODES * 4);
  int*    csr_src  = (int*)alloc(E_TOT * 4);
  int*    gstart   = (int*)alloc((NG + 1) * 4);
  int*    blocksum = (int*)alloc((SCAN_NB + 1) * 4);
  int*    blockoff = (int*)alloc((SCAN_NB + 1) * 4);
  float*  wa1      = (float*)alloc(64 * 16 * 4);
  float*  wa2      = (float*)alloc(64 * 16 * 4);
  ushort* w1pT     = (ushort*)alloc(64 * 512 * 2);
  ushort* w2pT     = (ushort*)alloc(64 * 512 * 2);
  float*  al       = (float*)alloc((size_t)N_NODES * 16 * 4);
  ushort* ewb      = (ushort*)alloc((size_t)E_TOT * 8 * 2);
  ushort* xbf      = (ushort*)alloc((size_t)N_NODES * 64 * 2);
  ushort* y1b      = (ushort*)alloc((size_t)N_NODES * 64 * 2);
  ushort* aggx     = (ushort*)alloc((size_t)N_NODES * 512 * 2);
  float*  y1p      = (float*)alloc((size_t)N_NODES * 64 * 4);
  float*  y1       = (float*)alloc((size_t)N_NODES * 64 * 4);
  float*  y2p      = y1p;  // y1p dead after layer-1 norm_relu
  float*  gstats   = (float*)alloc(8 * NG * 4);
  float*  pooled   = (float*)alloc(NG * 64 * 4);
  float* gs1 = gstats, *gss1 = gstats + NG, *gs2 = gstats + 2*NG, *gss2 = gstats + 3*NG;
  float* mean1 = gstats + 4*NG, *rstd1 = gstats + 5*NG, *mean2 = gstats + 6*NG, *rstd2 = gstats + 7*NG;

  hipMemsetAsync(counts, 0, N_NODES * 4, stream);
  hipMemsetAsync(cursor, 0, N_NODES * 4, stream);
  hipMemsetAsync(gstats, 0, 8 * NG * 4, stream);
  hipMemsetAsync(pooled, 0, NG * 64 * 4, stream);

  // prep
  prep_wa_kernel<<<4, 256, 0, stream>>>(W1, as1, ad1, wa1);
  prep_wa_kernel<<<4, 256, 0, stream>>>(W2, as2, ad2, wa2);
  prep_wpt_kernel<<<128, 256, 0, stream>>>(W1, w1pT);
  prep_wpt_kernel<<<128, 256, 0, stream>>>(W2, w2pT);
  tobf_kernel<<<(N_NODES * 64 / 8 + 255) / 256, 256, 0, stream>>>(x, xbf);

  // graph bounds (no atomics — batch is sorted)
  graph_bounds_kernel<<<(N_NODES + 256) / 256, 256, 0, stream>>>(batch, gstart);

  // CSR
  count_kernel<<<(E_TOT + 255) / 256, 256, 0, stream>>>(ei, counts);
  scan1_kernel<<<SCAN_NB, SCAN_B, 0, stream>>>(counts, row_off, blocksum);
  scan2_kernel<<<1, 64, 0, stream>>>(blocksum, blockoff);
  scan3_kernel<<<(N_NODES + 255) / 256, 256, 0, stream>>>(row_off, blockoff);
  scatter_kernel<<<(E_TOT + 255) / 256, 256, 0, stream>>>(ei, row_off, cursor, csr_src);

  const int aggBlocks  = (N_NODES + 3) / 4;
  const int waveBlocks = ((N_NODES + 15) / 16 * 64 + 255) / 256;
  const int gemmBlocks = (N_NODES + 63) / 64;

  // ---- layer 1 ----
  al_kernel<<<(N_NODES * 16 + 255) / 256, 256, 0, stream>>>(xbf, wa1, al);
  weights_kernel<<<aggBlocks, 256, 0, stream>>>(al, row_off, csr_src, ewb);
  agg2_kernel<<<aggBlocks, 256, 0, stream>>>(xbf, ewb, row_off, csr_src, aggx);
  outgemm_mfma_kernel<<<gemmBlocks, 256, 0, stream>>>(aggx, w1pT, b1, x, y1p);
  stats_kernel<<<waveBlocks, 256, 0, stream>>>(y1p, batch, gs1, gss1);
  finalize_kernel<<<1, 64, 0, stream>>>(gstart, gs1, gss1, mean1, rstd1);
  norm_relu_kernel<<<(N_NODES * 64 + 255) / 256, 256, 0, stream>>>(y1p, batch, mean1, rstd1, l1w, l1b, y1, y1b);

  // ---- layer 2 ----
  al_kernel<<<(N_NODES * 16 + 255) / 256, 256, 0, stream>>>(y1b, wa2, al);
  weights_kernel<<<aggBlocks, 256, 0, stream>>>(al, row_off, csr_src, ewb);
  agg2_kernel<<<aggBlocks, 256, 0, stream>>>(y1b, ewb, row_off, csr_src, aggx);
  outgemm_mfma_kernel<<<gemmBlocks, 256, 0, stream>>>(aggx, w2pT, b2, y1, y2p);
  stats_kernel<<<waveBlocks, 256, 0, stream>>>(y2p, batch, gs2, gss2);
  finalize_kernel<<<1, 64, 0, stream>>>(gstart, gs2, gss2, mean2, rstd2);
  norm_relu_pool_kernel<<<waveBlocks, 256, 0, stream>>>(y2p, batch, mean2, rstd2, l2w, l2b, pooled);

  // ---- head ----
  head_kernel<<<(NG * 32 + 255) / 256, 256, 0, stream>>>(pooled, gstart, Wh, bh, out);
}

// Round 6
// 249.979 us; speedup vs baseline: 3.4791x; 1.2926x over previous
//
#include <hip/hip_runtime.h>
#include <math.h>

#define N_NODES 50000
#define N_EDGES 400000
#define E_TOT   (N_EDGES + N_NODES)
#define NG      64
#define NEG_SLOPE 0.2f

typedef __attribute__((ext_vector_type(8))) short bf16x8;
typedef __attribute__((ext_vector_type(4))) float f32x4;

// ---------------- helpers ----------------
__device__ __forceinline__ float wave_sum(float v){
#pragma unroll
  for (int off = 32; off; off >>= 1) v += __shfl_xor(v, off, 64);
  return v;
}
__device__ __forceinline__ float lrelu(float x){ return x > 0.f ? x : NEG_SLOPE * x; }
__device__ __forceinline__ ushort f2bf(float f){
  union { float f; unsigned u; } v; v.f = f;
  unsigned r = v.u + 0x7FFFu + ((v.u >> 16) & 1u);  // RNE
  return (ushort)(r >> 16);
}
__device__ __forceinline__ float bf2f(ushort u){
  return __uint_as_float(((unsigned)u) << 16);
}
__device__ __forceinline__ float bflo(unsigned u){ return __uint_as_float(u << 16); }
__device__ __forceinline__ float bfhi(unsigned u){ return __uint_as_float(u & 0xffff0000u); }

__device__ __forceinline__ void acc8(float* acc, uint4 w, float xv){
  acc[0] = fmaf(bflo(w.x), xv, acc[0]);
  acc[1] = fmaf(bfhi(w.x), xv, acc[1]);
  acc[2] = fmaf(bflo(w.y), xv, acc[2]);
  acc[3] = fmaf(bfhi(w.y), xv, acc[3]);
  acc[4] = fmaf(bflo(w.z), xv, acc[4]);
  acc[5] = fmaf(bfhi(w.z), xv, acc[5]);
  acc[6] = fmaf(bflo(w.w), xv, acc[6]);
  acc[7] = fmaf(bfhi(w.w), xv, acc[7]);
}

// ---------------- prep: all weight transforms in ONE kernel ----------------
// [0,1024): wa1; [1024,2048): wa2; [2048, 2048+32768): w1pT; rest: w2pT
__global__ void prep_all_kernel(const float* __restrict__ W1, const float* __restrict__ as1,
                                const float* __restrict__ ad1, const float* __restrict__ W2,
                                const float* __restrict__ as2, const float* __restrict__ ad2,
                                float* __restrict__ wa1, float* __restrict__ wa2,
                                ushort* __restrict__ w1pT, ushort* __restrict__ w2pT){
  int idx = blockIdx.x * blockDim.x + threadIdx.x;
  if (idx < 2048){
    const float* W = (idx < 1024) ? W1 : W2;
    const float* asr = (idx < 1024) ? as1 : as2;
    const float* adr = (idx < 1024) ? ad1 : ad2;
    float* wa = (idx < 1024) ? wa1 : wa2;
    int i = idx & 1023;
    int k = i >> 4, c = i & 15;
    int h = c & 7;
    const float* a = (c < 8) ? asr : adr;
    float s = 0.f;
#pragma unroll
    for (int d = 0; d < 64; ++d) s = fmaf(W[k * 512 + h * 64 + d], a[h * 64 + d], s);
    wa[i] = s;
  } else if (idx < 2048 + 2 * 32768){
    int i = idx - 2048;
    const float* W = (i < 32768) ? W1 : W2;
    ushort* wpT = (i < 32768) ? w1pT : w2pT;
    i &= 32767;
    int j = i >> 9, k = i & 511;
    int h = k >> 6, d = k & 63;
    wpT[i] = f2bf(W[d * 512 + h * 64 + j] * 0.125f);
  }
}

// ---------------- graph boundaries from sorted batch (NO atomics) ----------------
__global__ void graph_bounds_kernel(const int* __restrict__ batch, int* __restrict__ gstart){
  int n = blockIdx.x * blockDim.x + threadIdx.x;
  if (n > N_NODES) return;
  int g = (n < N_NODES) ? batch[n] : NG;
  if (n == 0){
    for (int gg = 0; gg <= g; ++gg) gstart[gg] = 0;
  } else {
    int gp = batch[n - 1];
    for (int gg = gp + 1; gg <= g; ++gg) gstart[gg] = n;
  }
}

// ---------------- CSR build (by dst), shared across both layers ----------------
__global__ void count_kernel(const int* __restrict__ ei, int* __restrict__ counts){
  int e = blockIdx.x * blockDim.x + threadIdx.x;
  if (e >= E_TOT) return;
  int dst = (e < N_EDGES) ? ei[N_EDGES + e] : (e - N_EDGES);
  atomicAdd(&counts[dst], 1);
}

#define SCAN_B 1024
#define SCAN_NB ((N_NODES + SCAN_B - 1) / SCAN_B)   // 49

__global__ __launch_bounds__(SCAN_B) void scan1_kernel(const int* __restrict__ counts,
                                                       int* __restrict__ row_off,
                                                       int* __restrict__ blocksum){
  __shared__ int sh[SCAN_B];
  int i = blockIdx.x * SCAN_B + threadIdx.x;
  int v = (i < N_NODES) ? counts[i] : 0;
  sh[threadIdx.x] = v;
  __syncthreads();
#pragma unroll
  for (int off = 1; off < SCAN_B; off <<= 1){
    int add = (threadIdx.x >= (unsigned)off) ? sh[threadIdx.x - off] : 0;
    __syncthreads();
    sh[threadIdx.x] += add;
    __syncthreads();
  }
  if (i < N_NODES) row_off[i] = sh[threadIdx.x] - v;
  if (threadIdx.x == SCAN_B - 1) blocksum[blockIdx.x] = sh[SCAN_B - 1];
}

__global__ void scan2_kernel(int* __restrict__ blocksum, int* __restrict__ blockoff){
  __shared__ int sh[64];
  int t = threadIdx.x;
  int v = (t < SCAN_NB) ? blocksum[t] : 0;
  sh[t] = v;
  __syncthreads();
#pragma unroll
  for (int off = 1; off < 64; off <<= 1){
    int add = (t >= off) ? sh[t - off] : 0;
    __syncthreads();
    sh[t] += add;
    __syncthreads();
  }
  if (t < SCAN_NB) blockoff[t] = sh[t] - v;
  if (t == 63) blockoff[SCAN_NB] = sh[63];
}

__global__ void scan3_kernel(int* __restrict__ row_off, const int* __restrict__ blockoff){
  int i = blockIdx.x * blockDim.x + threadIdx.x;
  if (i < N_NODES) row_off[i] += blockoff[i >> 10];
  if (i == 0) row_off[N_NODES] = blockoff[SCAN_NB];
}

__global__ void scatter_kernel(const int* __restrict__ ei, const int* __restrict__ row_off,
                               int* __restrict__ cursor, int* __restrict__ csr_src){
  int e = blockIdx.x * blockDim.x + threadIdx.x;
  if (e >= E_TOT) return;
  int src, dst;
  if (e < N_EDGES){ src = ei[e]; dst = ei[N_EDGES + e]; }
  else            { src = dst = e - N_EDGES; }
  int pos = row_off[dst] + atomicAdd(&cursor[dst], 1);
  csr_src[pos] = src;
}

// ---------------- layer1 al from f32 x; also emits x as bf16 ----------------
__global__ void al1_kernel(const float* __restrict__ xin, const float* __restrict__ wa,
                           float* __restrict__ al, ushort* __restrict__ xbf){
  __shared__ float w[64 * 16];
  for (int i = threadIdx.x; i < 1024; i += blockDim.x) w[i] = wa[i];
  __syncthreads();
  int idx = blockIdx.x * blockDim.x + threadIdx.x;
  if (idx >= N_NODES * 16) return;
  int n = idx >> 4, c = idx & 15;
  const float* xr = xin + (size_t)n * 64;
  float s = 0.f;
  ushort ob[4];
#pragma unroll
  for (int k4 = 0; k4 < 16; ++k4){
    float4 v = *(const float4*)(xr + k4 * 4);
    s = fmaf(v.x, w[(k4 * 4 + 0) * 16 + c], s);
    s = fmaf(v.y, w[(k4 * 4 + 1) * 16 + c], s);
    s = fmaf(v.z, w[(k4 * 4 + 2) * 16 + c], s);
    s = fmaf(v.w, w[(k4 * 4 + 3) * 16 + c], s);
    if (k4 == c >> 2){  // this thread owns cols [c*4, c*4+4)
      int rot = c & 3;  // k4*4 == (c>>2)*4; we need cols c*4..c*4+3 -> k4 = c
    }
  }
  // write bf16 for cols [c*4, c*4+4)
  float4 mine = *(const float4*)(xr + c * 4);
  ob[0] = f2bf(mine.x); ob[1] = f2bf(mine.y); ob[2] = f2bf(mine.z); ob[3] = f2bf(mine.w);
  *(ushort4*)(xbf + (size_t)n * 64 + c * 4) = *(const ushort4*)ob;
  al[idx] = s;
}

// ---------------- layer2 al from bf16 ----------------
__global__ void al2_kernel(const ushort* __restrict__ xin, const float* __restrict__ wa,
                           float* __restrict__ al){
  __shared__ float w[64 * 16];
  for (int i = threadIdx.x; i < 1024; i += blockDim.x) w[i] = wa[i];
  __syncthreads();
  int idx = blockIdx.x * blockDim.x + threadIdx.x;
  if (idx >= N_NODES * 16) return;
  int n = idx >> 4, c = idx & 15;
  const ushort* xr = xin + (size_t)n * 64;
  float s = 0.f;
#pragma unroll
  for (int k8 = 0; k8 < 8; ++k8){
    uint4 u = *(const uint4*)(xr + k8 * 8);
    unsigned uu[4] = {u.x, u.y, u.z, u.w};
#pragma unroll
    for (int j = 0; j < 4; ++j){
      int k = k8 * 8 + j * 2;
      s = fmaf(bflo(uu[j]), w[k * 16 + c], s);
      s = fmaf(bfhi(uu[j]), w[(k + 1) * 16 + c], s);
    }
  }
  al[idx] = s;
}

// ---------------- normalized softmax weights -> bf16 ----------------
// wave per node; lane = eo*8 + h. Fast path: degree <= 64 (exp cached in regs).
__global__ void weights_kernel(const float* __restrict__ al, const int* __restrict__ row_off,
                               const int* __restrict__ csr_src, ushort* __restrict__ ewb){
  int wid = (int)((blockIdx.x * blockDim.x + threadIdx.x) >> 6);
  int lane = threadIdx.x & 63;
  if (wid >= N_NODES) return;
  const int n = wid;
  const int eo = lane >> 3, h = lane & 7;
  const int s0 = row_off[n], s1 = row_off[n + 1];
  const float ald = al[n * 16 + 8 + h];

  if (s1 - s0 <= 64){
    float wv[8];
    float sum = 0.f;
#pragma unroll
    for (int i = 0; i < 8; ++i){
      int e = s0 + eo + i * 8;
      float v = 0.f;
      if (e < s1){
        int s = csr_src[e];
        v = __expf(lrelu(al[s * 16 + h] + ald));
      }
      wv[i] = v;
      sum += v;
    }
#pragma unroll
    for (int off = 8; off < 64; off <<= 1) sum += __shfl_xor(sum, off, 64);
    float inv = 1.f / (sum + 1e-16f);
#pragma unroll
    for (int i = 0; i < 8; ++i){
      int e = s0 + eo + i * 8;
      if (e < s1) ewb[(size_t)e * 8 + h] = f2bf(wv[i] * inv);
    }
  } else {
    float sum = 0.f;
    for (int e = s0 + eo; e < s1; e += 8){
      int s = csr_src[e];
      sum += __expf(lrelu(al[s * 16 + h] + ald));
    }
#pragma unroll
    for (int off = 8; off < 64; off <<= 1) sum += __shfl_xor(sum, off, 64);
    float inv = 1.f / (sum + 1e-16f);
    for (int e = s0 + eo; e < s1; e += 8){
      int s = csr_src[e];
      ewb[(size_t)e * 8 + h] = f2bf(__expf(lrelu(al[s * 16 + h] + ald)) * inv);
    }
  }
}

// ---------------- aggregation: wave per node, lane = dim; unroll 4 ----------------
__global__ void agg2_kernel(const ushort* __restrict__ xb, const ushort* __restrict__ ewb,
                            const int* __restrict__ row_off, const int* __restrict__ csr_src,
                            ushort* __restrict__ aggx){
  int wid = (int)((blockIdx.x * blockDim.x + threadIdx.x) >> 6);
  int lane = threadIdx.x & 63;
  if (wid >= N_NODES) return;
  const int n = wid;
  const int s0 = row_off[n], s1 = row_off[n + 1];
  float acc[8];
#pragma unroll
  for (int h = 0; h < 8; ++h) acc[h] = 0.f;

  int e = s0;
  for (; e + 4 <= s1; e += 4){
    int sa = csr_src[e], sb = csr_src[e + 1], sc = csr_src[e + 2], sd = csr_src[e + 3];
    float xa = bf2f(xb[(size_t)sa * 64 + lane]);
    float xc = bf2f(xb[(size_t)sb * 64 + lane]);
    float xe = bf2f(xb[(size_t)sc * 64 + lane]);
    float xg = bf2f(xb[(size_t)sd * 64 + lane]);
    uint4 wa = *(const uint4*)(ewb + (size_t)e * 8);
    uint4 wb = *(const uint4*)(ewb + (size_t)(e + 1) * 8);
    uint4 wc = *(const uint4*)(ewb + (size_t)(e + 2) * 8);
    uint4 wd = *(const uint4*)(ewb + (size_t)(e + 3) * 8);
    acc8(acc, wa, xa);
    acc8(acc, wb, xc);
    acc8(acc, wc, xe);
    acc8(acc, wd, xg);
  }
  for (; e < s1; ++e){
    int sa = csr_src[e];
    float xa = bf2f(xb[(size_t)sa * 64 + lane]);
    uint4 wa = *(const uint4*)(ewb + (size_t)e * 8);
    acc8(acc, wa, xa);
  }
#pragma unroll
  for (int h = 0; h < 8; ++h)
    aggx[(size_t)n * 512 + h * 64 + lane] = f2bf(acc[h]);
}

// ---------------- Y = aggx(bf16) @ W'(bf16) + bias + res via MFMA; fused LN stats ----------------
__global__ __launch_bounds__(256) void outgemm_stats_kernel(const ushort* __restrict__ A,
                                                            const ushort* __restrict__ BT,
                                                            const float* __restrict__ bias,
                                                            const float* __restrict__ res,
                                                            const int* __restrict__ batch,
                                                            float* __restrict__ Y,
                                                            float* __restrict__ gs,
                                                            float* __restrict__ gss){
  __shared__ ushort Al[64][136];  // +8 pad
  __shared__ ushort Bl[64][136];
  __shared__ float gsl[NG], gssl[NG];
  const int t = threadIdx.x;
  const int wave = t >> 6, lane = t & 63;
  const int rowbase = blockIdx.x * 64;
  const int frow = lane & 15, kc = lane >> 4;
  if (t < NG){ gsl[t] = 0.f; gssl[t] = 0.f; }
  f32x4 acc[4];
#pragma unroll
  for (int ct = 0; ct < 4; ++ct) acc[ct] = (f32x4){0.f, 0.f, 0.f, 0.f};

  for (int k0 = 0; k0 < 512; k0 += 128){
#pragma unroll
    for (int ppass = 0; ppass < 4; ++ppass){
      int idx = (ppass * 256 + t) * 8;
      int r = idx >> 7, k = idx & 127;
      int grow = rowbase + r;
      uint4 v = make_uint4(0u, 0u, 0u, 0u);
      if (grow < N_NODES) v = *(const uint4*)(A + (size_t)grow * 512 + k0 + k);
      *(uint4*)&Al[r][k] = v;
      uint4 w = *(const uint4*)(BT + (size_t)r * 512 + k0 + k);
      *(uint4*)&Bl[r][k] = w;
    }
    __syncthreads();
#pragma unroll
    for (int kf = 0; kf < 4; ++kf){
      bf16x8 a = *(const bf16x8*)&Al[wave * 16 + frow][kf * 32 + kc * 8];
#pragma unroll
      for (int ct = 0; ct < 4; ++ct){
        bf16x8 b = *(const bf16x8*)&Bl[ct * 16 + frow][kf * 32 + kc * 8];
        acc[ct] = __builtin_amdgcn_mfma_f32_16x16x32_bf16(a, b, acc[ct], 0, 0, 0);
      }
    }
    __syncthreads();
  }
  const int col0 = lane & 15, rsub = (lane >> 4) * 4;
  float rs[4] = {0.f, 0.f, 0.f, 0.f}, rss[4] = {0.f, 0.f, 0.f, 0.f};
#pragma unroll
  for (int ct = 0; ct < 4; ++ct){
    int col = ct * 16 + col0;
    float bs = bias[col];
#pragma unroll
    for (int j = 0; j < 4; ++j){
      int grow = rowbase + wave * 16 + rsub + j;
      if (grow < N_NODES){
        float y = acc[ct][j] + bs + res[(size_t)grow * 64 + col];
        Y[(size_t)grow * 64 + col] = y;
        rs[j] += y;
        rss[j] = fmaf(y, y, rss[j]);
      }
    }
  }
  // reduce row sums over the 16 col-lanes (lane^off keeps lane>>4 fixed for off<16)
#pragma unroll
  for (int j = 0; j < 4; ++j){
#pragma unroll
    for (int off = 1; off < 16; off <<= 1){
      rs[j] += __shfl_xor(rs[j], off, 64);
      rss[j] += __shfl_xor(rss[j], off, 64);
    }
  }
  if (col0 == 0){
#pragma unroll
    for (int j = 0; j < 4; ++j){
      int grow = rowbase + wave * 16 + rsub + j;
      if (grow < N_NODES){
        int g = batch[grow];
        atomicAdd(&gsl[g], rs[j]);
        atomicAdd(&gssl[g], rss[j]);
      }
    }
  }
  __syncthreads();
  if (t < NG && (gsl[t] != 0.f || gssl[t] != 0.f)){
    atomicAdd(&gs[t], gsl[t]);
    atomicAdd(&gss[t], gssl[t]);
  }
}

// ---------------- normalize + relu (layer 1): f32 + bf16 outputs; inline finalize ----------------
__global__ void norm_relu_kernel(const float* __restrict__ Y, const int* __restrict__ batch,
                                 const int* __restrict__ gstart, const float* __restrict__ gs,
                                 const float* __restrict__ gss,
                                 const float* __restrict__ lw, const float* __restrict__ lb,
                                 float* __restrict__ out, ushort* __restrict__ outb){
  int idx = blockIdx.x * blockDim.x + threadIdx.x;
  if (idx >= N_NODES * 64) return;
  int n = idx >> 6, c = idx & 63;
  int g = batch[n];
  float cnt = (float)(gstart[g + 1] - gstart[g]);
  float norm = fmaxf(cnt, 1.f) * 64.f;
  float m = gs[g] / norm;
  float var = fmaxf(gss[g] / norm - m * m, 0.f);
  float rstd = rsqrtf(var + 1e-5f);
  float v = (Y[idx] - m) * rstd * lw[c] + lb[c];
  float r = fmaxf(v, 0.f);
  out[idx] = r;
  outb[idx] = f2bf(r);
}

// ---------------- normalize + relu + pooled accumulation (layer 2); inline finalize ----------------
__global__ void norm_relu_pool_kernel(const float* __restrict__ Y, const int* __restrict__ batch,
                                      const int* __restrict__ gstart, const float* __restrict__ gs,
                                      const float* __restrict__ gss,
                                      const float* __restrict__ lw, const float* __restrict__ lb,
                                      float* __restrict__ pooled){
  int w = (int)((blockIdx.x * blockDim.x + threadIdx.x) >> 6);
  int lane = threadIdx.x & 63;
  int nbase = w * 16;
  if (nbase >= N_NODES) return;
  int nend = min(nbase + 16, N_NODES);
  float accv = 0.f;
  int g = batch[nbase];
  float cnt = (float)(gstart[g + 1] - gstart[g]);
  float norm = fmaxf(cnt, 1.f) * 64.f;
  float m = gs[g] / norm;
  float var = fmaxf(gss[g] / norm - m * m, 0.f);
  float rstd = rsqrtf(var + 1e-5f);
  for (int n = nbase; n < nend; ++n){
    int gn = batch[n];
    if (gn != g){
      atomicAdd(&pooled[g * 64 + lane], accv);
      accv = 0.f; g = gn;
      cnt = (float)(gstart[g + 1] - gstart[g]);
      norm = fmaxf(cnt, 1.f) * 64.f;
      m = gs[g] / norm;
      var = fmaxf(gss[g] / norm - m * m, 0.f);
      rstd = rsqrtf(var + 1e-5f);
    }
    float v = (Y[(size_t)n * 64 + lane] - m) * rstd * lw[lane] + lb[lane];
    accv += fmaxf(v, 0.f);
  }
  atomicAdd(&pooled[g * 64 + lane], accv);
}

// ---------------- head ----------------
__global__ void head_kernel(const float* __restrict__ pooled, const int* __restrict__ gstart,
                            const float* __restrict__ Wh, const float* __restrict__ bh,
                            float* __restrict__ out){
  int idx = blockIdx.x * blockDim.x + threadIdx.x;
  if (idx >= NG * 32) return;
  int g = idx >> 5, o = idx & 31;
  float cnt = (float)(gstart[g + 1] - gstart[g]);
  float inv = 1.f / fmaxf(cnt, 1.f);
  float s = 0.f;
#pragma unroll
  for (int d = 0; d < 64; ++d) s = fmaf(pooled[g * 64 + d] * inv, Wh[d * 32 + o], s);
  out[idx] = fmaxf(s + bh[o], 0.f);
}

// ---------------- launch ----------------
extern "C" void kernel_launch(void* const* d_in, const int* in_sizes, int n_in,
                              void* d_out, int out_size, void* d_ws, size_t ws_size,
                              hipStream_t stream){
  const float* x     = (const float*)d_in[0];
  const int*   ei    = (const int*)d_in[1];
  const int*   batch = (const int*)d_in[2];
  const float* W1    = (const float*)d_in[3];
  const float* as1   = (const float*)d_in[4];
  const float* ad1   = (const float*)d_in[5];
  const float* b1    = (const float*)d_in[6];
  const float* l1w   = (const float*)d_in[7];
  const float* l1b   = (const float*)d_in[8];
  const float* W2    = (const float*)d_in[9];
  const float* as2   = (const float*)d_in[10];
  const float* ad2   = (const float*)d_in[11];
  const float* b2    = (const float*)d_in[12];
  const float* l2w   = (const float*)d_in[13];
  const float* l2b   = (const float*)d_in[14];
  const float* Wh    = (const float*)d_in[15];
  const float* bh    = (const float*)d_in[16];
  float* out = (float*)d_out;

  char* p = (char*)d_ws;
  auto alloc = [&](size_t bytes) -> void* {
    void* r = (void*)p;
    p += (bytes + 255) & ~(size_t)255;
    return r;
  };
  int*    counts   = (int*)alloc(N_NODES * 4);
  int*    cursor   = (int*)alloc(N_NODES * 4);   // adjacent to counts: one memset
  int*    row_off  = (int*)alloc((N_NODES + 1) * 4);
  int*    csr_src  = (int*)alloc(E_TOT * 4);
  int*    gstart   = (int*)alloc((NG + 1) * 4);
  int*    blocksum = (int*)alloc((SCAN_NB + 1) * 4);
  int*    blockoff = (int*)alloc((SCAN_NB + 1) * 4);
  float*  wa1      = (float*)alloc(64 * 16 * 4);
  float*  wa2      = (float*)alloc(64 * 16 * 4);
  ushort* w1pT     = (ushort*)alloc(64 * 512 * 2);
  ushort* w2pT     = (ushort*)alloc(64 * 512 * 2);
  float*  al       = (float*)alloc((size_t)N_NODES * 16 * 4);
  ushort* ewb      = (ushort*)alloc((size_t)E_TOT * 8 * 2);
  ushort* xbf      = (ushort*)alloc((size_t)N_NODES * 64 * 2);
  ushort* y1b      = (ushort*)alloc((size_t)N_NODES * 64 * 2);
  ushort* aggx     = (ushort*)alloc((size_t)N_NODES * 512 * 2);
  float*  y1p      = (float*)alloc((size_t)N_NODES * 64 * 4);
  float*  y1       = (float*)alloc((size_t)N_NODES * 64 * 4);
  float*  y2p      = y1p;  // y1p dead after layer-1 norm_relu
  float*  gstats   = (float*)alloc(8 * NG * 4);
  float*  pooled   = (float*)alloc(NG * 64 * 4);  // adjacent to gstats: one memset
  float* gs1 = gstats, *gss1 = gstats + NG, *gs2 = gstats + 2*NG, *gss2 = gstats + 3*NG;

  hipMemsetAsync(counts, 0, (size_t)((char*)row_off - (char*)counts), stream);
  hipMemsetAsync(gstats, 0, (size_t)((char*)pooled - (char*)gstats) + NG * 64 * 4, stream);

  // prep (single kernel)
  prep_all_kernel<<<(2048 + 2 * 32768 + 255) / 256, 256, 0, stream>>>(
      W1, as1, ad1, W2, as2, ad2, wa1, wa2, w1pT, w2pT);

  // graph bounds (no atomics — batch is sorted)
  graph_bounds_kernel<<<(N_NODES + 256) / 256, 256, 0, stream>>>(batch, gstart);

  // CSR
  count_kernel<<<(E_TOT + 255) / 256, 256, 0, stream>>>(ei, counts);
  scan1_kernel<<<SCAN_NB, SCAN_B, 0, stream>>>(counts, row_off, blocksum);
  scan2_kernel<<<1, 64, 0, stream>>>(blocksum, blockoff);
  scan3_kernel<<<(N_NODES + 255) / 256, 256, 0, stream>>>(row_off, blockoff);
  scatter_kernel<<<(E_TOT + 255) / 256, 256, 0, stream>>>(ei, row_off, cursor, csr_src);

  const int aggBlocks  = (N_NODES + 3) / 4;
  const int waveBlocks = ((N_NODES + 15) / 16 * 64 + 255) / 256;
  const int gemmBlocks = (N_NODES + 63) / 64;

  // ---- layer 1 ----
  al1_kernel<<<(N_NODES * 16 + 255) / 256, 256, 0, stream>>>(x, wa1, al, xbf);
  weights_kernel<<<aggBlocks, 256, 0, stream>>>(al, row_off, csr_src, ewb);
  agg2_kernel<<<aggBlocks, 256, 0, stream>>>(xbf, ewb, row_off, csr_src, aggx);
  outgemm_stats_kernel<<<gemmBlocks, 256, 0, stream>>>(aggx, w1pT, b1, x, batch, y1p, gs1, gss1);
  norm_relu_kernel<<<(N_NODES * 64 + 255) / 256, 256, 0, stream>>>(y1p, batch, gstart, gs1, gss1, l1w, l1b, y1, y1b);

  // ---- layer 2 ----
  al2_kernel<<<(N_NODES * 16 + 255) / 256, 256, 0, stream>>>(y1b, wa2, al);
  weights_kernel<<<aggBlocks, 256, 0, stream>>>(al, row_off, csr_src, ewb);
  agg2_kernel<<<aggBlocks, 256, 0, stream>>>(y1b, ewb, row_off, csr_src, aggx);
  outgemm_stats_kernel<<<gemmBlocks, 256, 0, stream>>>(aggx, w2pT, b2, y1, batch, y2p, gs2, gss2);
  norm_relu_pool_kernel<<<waveBlocks, 256, 0, stream>>>(y2p, batch, gstart, gs2, gss2, l2w, l2b, pooled);

  // ---- head ----
  head_kernel<<<(NG * 32 + 255) / 256, 256, 0, stream>>>(pooled, gstart, Wh, bh, out);
}